// Round 3
// baseline (341.812 us; speedup 1.0000x reference)
//
#include <hip/hip_runtime.h>

typedef unsigned short u16;
typedef unsigned int u32;

typedef __attribute__((ext_vector_type(8))) short bfrag;   // 8 bf16 for MFMA A/B
typedef __attribute__((ext_vector_type(4))) float f32x4;
typedef __attribute__((ext_vector_type(8))) u16 u16x8;
typedef __attribute__((ext_vector_type(4))) u16 u16x4;

constexpr int S = 2048;
constexpr int HN = 16;

__device__ __forceinline__ u16 f2b(float f) {
  u32 u = __builtin_bit_cast(u32, f);
  return (u16)((u + 0x7FFFu + ((u >> 16) & 1u)) >> 16);  // RNE f32->bf16
}
__device__ __forceinline__ float b2f(u16 v) {
  u32 u = (u32)v << 16;
  return __builtin_bit_cast(float, u);
}
__device__ __forceinline__ u32 cvtpk(float lo, float hi) {
  u32 d;
  asm("v_cvt_pk_bf16_f32 %0, %1, %2" : "=v"(d) : "v"(lo), "v"(hi));
  return d;
}

__device__ __forceinline__ f32x4 mfma16(bfrag a, bfrag b, f32x4 c) {
  return __builtin_amdgcn_mfma_f32_16x16x32_bf16(a, b, c, 0, 0, 0);
}

__device__ __forceinline__ void gload_lds16(const void* g, void* l) {
  __builtin_amdgcn_global_load_lds(
      (const __attribute__((address_space(1))) u32*)g,
      (__attribute__((address_space(3))) u32*)l, 16, 0, 0);
}

// ---------------- W transpose + f32->bf16:  WT[n][k] = (bf16) W[k][n] ----------------
__global__ __launch_bounds__(256) void wtrans_kernel(
    const float* __restrict__ W0, const float* __restrict__ W1,
    const float* __restrict__ W2, const float* __restrict__ W3,
    u16* __restrict__ ws)
{
  const float* W = blockIdx.z == 0 ? W0 : blockIdx.z == 1 ? W1 : blockIdx.z == 2 ? W2 : W3;
  u16* WT = ws + (size_t)blockIdx.z * (1u << 20);
  __shared__ u16 tile[64 * 65];
  const int t = threadIdx.x;
  const int k0 = blockIdx.y * 64, n0 = blockIdx.x * 64;
#pragma unroll
  for (int i = 0; i < 4; ++i) {
    int idx = i * 256 + t;
    int r = idx >> 4, c4 = (idx & 15) * 4;
    float4 v = *(const float4*)&W[(size_t)(k0 + r) * 1024 + n0 + c4];
    tile[r * 65 + c4 + 0] = f2b(v.x);
    tile[r * 65 + c4 + 1] = f2b(v.y);
    tile[r * 65 + c4 + 2] = f2b(v.z);
    tile[r * 65 + c4 + 3] = f2b(v.w);
  }
  __syncthreads();
#pragma unroll
  for (int i = 0; i < 2; ++i) {
    int idx = i * 256 + t;
    int n = idx >> 3, k8 = (idx & 7) * 8;
    u16x8 o;
#pragma unroll
    for (int j = 0; j < 8; ++j) o[j] = tile[(k8 + j) * 65 + n];
    *(u16x8*)&WT[(size_t)(n0 + n) * 1024 + k0 + k8] = o;
  }
}

// ---------------- v [B,H,S,64] -> vT [B,H,64,S] (bf16) ----------------
__global__ __launch_bounds__(256) void vtrans_kernel(
    const u16* __restrict__ v, u16* __restrict__ vT)
{
  __shared__ u16 tile[64 * 65];
  const int t = threadIdx.x;
  const int s0 = blockIdx.x * 64;
  const int bh = blockIdx.y;
#pragma unroll
  for (int i = 0; i < 2; ++i) {
    int idx = i * 256 + t;
    int r = idx >> 3, c8 = (idx & 7) * 8;
    u16x8 in = *(const u16x8*)&v[((size_t)bh * S + s0 + r) * 64 + c8];
#pragma unroll
    for (int j = 0; j < 8; ++j) tile[r * 65 + c8 + j] = in[j];
  }
  __syncthreads();
#pragma unroll
  for (int i = 0; i < 2; ++i) {
    int idx = i * 256 + t;
    int d = idx >> 3, s8 = (idx & 7) * 8;
    u16x8 o;
#pragma unroll
    for (int j = 0; j < 8; ++j) o[j] = tile[(s8 + j) * 65 + d];
    *(u16x8*)&vT[((size_t)bh * 64 + d) * S + s0 + s8] = o;
  }
}

// ---------------- shared GEMM core: C[M,N] = A[M,K] * Bt[N,K]^T + bias ----------------
// AMODE 0: A f32 (convert to bf16 while staging); 1: A bf16.
// CMODE 0: scatter-store bf16 to [B,H,S,64]; 1: f32 linear [M,N].
template <int AMODE, int CMODE>
__device__ __forceinline__ void gemm_core(
    u16* As, u16* Bs,
    const void* __restrict__ Av, const u16* __restrict__ Bt,
    const float* __restrict__ bias, void* __restrict__ Cout,
    int N, int K, int bn, int bm)
{
  const int tid = threadIdx.x;
  const int wid = tid >> 6, lane = tid & 63;
  const int g = lane >> 4, c = lane & 15;
  const int wr = wid >> 1, wc = wid & 1;

  f32x4 acc[4][4] = {};

  const int nkt = K >> 6;
  for (int kt = 0; kt < nkt; ++kt) {
    if (AMODE == 0) {
      const float* A = (const float*)Av;
#pragma unroll
      for (int p = 0; p < 4; ++p) {
        int e = (p * 256 + tid) * 8;
        int row = e >> 6, col = e & 63;
        const float* src = &A[(size_t)(bm * 128 + row) * K + kt * 64 + col];
        float4 v0 = *(const float4*)src;
        float4 v1 = *(const float4*)(src + 4);
        u16x8 w;
        w[0] = f2b(v0.x); w[1] = f2b(v0.y); w[2] = f2b(v0.z); w[3] = f2b(v0.w);
        w[4] = f2b(v1.x); w[5] = f2b(v1.y); w[6] = f2b(v1.z); w[7] = f2b(v1.w);
        *(u16x8*)&As[row * 64 + (col ^ ((row & 7) << 3))] = w;
      }
    } else {
      const u16* A = (const u16*)Av;
#pragma unroll
      for (int p = 0; p < 4; ++p) {
        int e = (p * 256 + tid) * 8;
        int row = e >> 6, col = e & 63;
        u16x8 w = *(const u16x8*)&A[(size_t)(bm * 128 + row) * K + kt * 64 + col];
        *(u16x8*)&As[row * 64 + (col ^ ((row & 7) << 3))] = w;
      }
    }
#pragma unroll
    for (int p = 0; p < 4; ++p) {
      int off = (p * 4 + wid) * 1024 + (lane << 4);
      int row = off >> 7, colb = off & 127;
      const u16* src = &Bt[(size_t)(bn * 128 + row) * K + kt * 64 +
                           ((colb ^ ((row & 7) << 4)) >> 1)];
      gload_lds16(src, (char*)Bs + (p * 4 + wid) * 1024);
    }
    __syncthreads();

#pragma unroll
    for (int ks = 0; ks < 2; ++ks) {
      bfrag af[4], bf[4];
#pragma unroll
      for (int mi = 0; mi < 4; ++mi) {
        int row = wr * 64 + mi * 16 + c;
        af[mi] = *(const bfrag*)&As[row * 64 + ((ks * 32 + g * 8) ^ ((row & 7) << 3))];
      }
#pragma unroll
      for (int ni = 0; ni < 4; ++ni) {
        int row = wc * 64 + ni * 16 + c;
        bf[ni] = *(const bfrag*)&Bs[row * 64 + ((ks * 32 + g * 8) ^ ((row & 7) << 3))];
      }
#pragma unroll
      for (int mi = 0; mi < 4; ++mi)
#pragma unroll
        for (int ni = 0; ni < 4; ++ni)
          acc[mi][ni] = mfma16(af[mi], bf[ni], acc[mi][ni]);
    }
    __syncthreads();
  }

#pragma unroll
  for (int mi = 0; mi < 4; ++mi) {
#pragma unroll
    for (int ni = 0; ni < 4; ++ni) {
#pragma unroll
      for (int j = 0; j < 4; ++j) {
        int rowg = bm * 128 + wr * 64 + mi * 16 + g * 4 + j;
        int colg = bn * 128 + wc * 64 + ni * 16 + c;
        float val = acc[mi][ni][j] + bias[colg];
        if (CMODE == 0) {
          int b = rowg >> 11, s = rowg & (S - 1);
          int h = colg >> 6, d = colg & 63;
          ((u16*)Cout)[((size_t)((b * HN + h) * S + s)) * 64 + d] = f2b(val);
        } else {
          ((float*)Cout)[(size_t)rowg * N + colg] = val;
        }
      }
    }
  }
}

// fused Q/K/V projection: blockIdx.z selects which
__global__ __launch_bounds__(256) void qkv_gemm(
    const float* __restrict__ A0, const float* __restrict__ A1, const float* __restrict__ A2,
    const u16* __restrict__ WTbase,
    const float* __restrict__ b0, const float* __restrict__ b1, const float* __restrict__ b2,
    u16* __restrict__ wsbase)
{
  __shared__ __align__(16) u16 As[128 * 64];
  __shared__ __align__(16) u16 Bs[128 * 64];
  const int z = blockIdx.z;
  const float* A = z == 0 ? A0 : z == 1 ? A1 : A2;
  const u16* Bt = WTbase + (size_t)z * (1u << 20);
  const float* bias = z == 0 ? b0 : z == 1 ? b1 : b2;
  u16* C = wsbase + (size_t)(4 + 4 * z) * (1u << 20);
  gemm_core<0, 0>(As, Bs, A, Bt, bias, C, 1024, 1024, blockIdx.x, blockIdx.y);
}

__global__ __launch_bounds__(256) void out_gemm(
    const u16* __restrict__ Av, const u16* __restrict__ Bt,
    const float* __restrict__ bias, void* __restrict__ Cout)
{
  __shared__ __align__(16) u16 As[128 * 64];
  __shared__ __align__(16) u16 Bs[128 * 64];
  gemm_core<1, 1>(As, Bs, Av, Bt, bias, Cout, 1024, 1024, blockIdx.x, blockIdx.y);
}

// ---------------- column sum of v over all S (for fully-masked-row fixup) ----------------
__global__ __launch_bounds__(256) void colsum_kernel(
    const u16* __restrict__ v, float* __restrict__ colsumg)
{
  __shared__ float red[256];
  const int tid = threadIdx.x;
  const int bh = blockIdx.x;
  const int col = tid & 63, chunk = tid >> 6;
  float s = 0.f;
  for (int i = chunk; i < S; i += 4)
    s += b2f(v[((size_t)bh * S + i) * 64 + col]);
  red[tid] = s;
  __syncthreads();
  if (tid < 64)
    colsumg[bh * 64 + col] = red[col] + red[64 + col] + red[128 + col] + red[192 + col];
}

// rows with all-pad causal prefix: reference softmax is uniform over ALL 2048 keys
__global__ __launch_bounds__(256) void fixup_kernel(
    const int* __restrict__ pad, const float* __restrict__ colsumg, u16* __restrict__ ao)
{
  __shared__ int fzs;
  const int tid = threadIdx.x;
  const int b = blockIdx.x;
  if (tid == 0) fzs = S;
  __syncthreads();
  int local = S;
  for (int i = tid; i < S; i += 256)
    if (pad[b * S + i] == 0) local = min(local, i);
  atomicMin(&fzs, local);
  __syncthreads();
  const int fz = fzs;
  for (int idx = tid; idx < fz * 1024; idx += 256) {
    int row = idx >> 10, col = idx & 1023;
    int h = col >> 6, d = col & 63;
    ao[((size_t)b * S + row) * 1024 + col] = f2b(colsumg[(b * 16 + h) * 64 + d] * (1.f / 2048.f));
  }
}

// ---------------- flash attention, causal tiles only, swapped-operand MFMA ----------------
// QK^T computed as mfma(K,Q) -> lane owns one q-row (c); PV as mfma(V,P) with V's key
// axis stored PERMUTED in LDS (slot = key with nf/g bitfields swapped) so P feeds MFMA
// straight from registers (no cross-lane exchange needed).
__global__ __launch_bounds__(256) void attn_kernel(
    const u16* __restrict__ q, const u16* __restrict__ k,
    const u16* __restrict__ vT, const int* __restrict__ pad,
    u16* __restrict__ ao)
{
  __shared__ __align__(16) u16 Ks[64 * 64];
  __shared__ __align__(16) u16 Vs[64 * 64];
  __shared__ __align__(16) float biasS[2048];

  const int tid = threadIdx.x;
  const int wid = tid >> 6, lane = tid & 63;
  const int g = lane >> 4, c = lane & 15;
  const int qt = blockIdx.x, bh = blockIdx.y;
  const int b = bh >> 4, h = bh & 15;

  // pad bias (read each tile as float4 broadcast)
  for (int i = tid; i < S; i += 256)
    biasS[i] = pad[b * S + i] ? -1e9f : 0.f;

  const int qrow = qt * 64 + wid * 16 + c;
  bfrag qf[2];
#pragma unroll
  for (int ks = 0; ks < 2; ++ks)
    qf[ks] = *(const bfrag*)&q[((size_t)bh * S + qrow) * 64 + ks * 32 + g * 8];

  float m = -3.0e38f, lsum = 0.f;
  f32x4 acc[4] = {};

  for (int kt = 0; kt <= qt; ++kt) {
    // stage K [64 keys][64 d] via global_load_lds, XOR-swizzled (pre-swizzled source)
#pragma unroll
    for (int p = 0; p < 2; ++p) {
      int off = (wid * 2 + p) * 1024 + (lane << 4);
      int row = off >> 7, colb = off & 127;
      gload_lds16(&k[((size_t)bh * S + kt * 64 + row) * 64 + ((colb ^ ((row & 7) << 4)) >> 1)],
                  (char*)Ks + (wid * 2 + p) * 1024);
    }
    // stage V^T [64 dv][64 keys] reg-staged, key axis permuted (slot = swap nf/g fields)
    // + XOR swizzle per dv row. key=32ks+16nf+4g+r  ->  slot=32ks+8g+4nf+r.
#pragma unroll
    for (int p = 0; p < 2; ++p) {
      int e = p * 256 + tid;
      int dv = e >> 3, key0 = (e & 7) << 3;
      u16x8 w = *(const u16x8*)&vT[((size_t)bh * 64 + dv) * S + kt * 64 + key0];
      int ks_ = key0 >> 5, nf_ = (key0 >> 4) & 1, g0 = (key0 >> 2) & 3;
      int s0 = ks_ * 32 + g0 * 8 + nf_ * 4;
      int s1 = ks_ * 32 + (g0 + 1) * 8 + nf_ * 4;
      int x = (dv & 7) << 3;
      u16x4 lo = {w[0], w[1], w[2], w[3]};
      u16x4 hi = {w[4], w[5], w[6], w[7]};
      *(u16x4*)&Vs[dv * 64 + (s0 ^ x)] = lo;
      *(u16x4*)&Vs[dv * 64 + (s1 ^ x)] = hi;
    }
    __syncthreads();

    // QK^T swapped: D[key][qrow], col=c=qrow, row=g*4+r (+16nf)
    f32x4 sc[4] = {};
#pragma unroll
    for (int ks = 0; ks < 2; ++ks) {
#pragma unroll
      for (int nf = 0; nf < 4; ++nf) {
        int row = nf * 16 + c;
        bfrag kf = *(const bfrag*)&Ks[row * 64 + ((ks * 32 + g * 8) ^ ((row & 7) << 3))];
        sc[nf] = mfma16(kf, qf[ks], sc[nf]);
      }
    }

    // mask: score = s/8 + padbias; diagonal tile adds causal
    float sval[4][4];
#pragma unroll
    for (int nf = 0; nf < 4; ++nf) {
      float4 kb4 = *(const float4*)&biasS[kt * 64 + nf * 16 + g * 4];
      sval[nf][0] = fmaf(sc[nf][0], 0.125f, kb4.x);
      sval[nf][1] = fmaf(sc[nf][1], 0.125f, kb4.y);
      sval[nf][2] = fmaf(sc[nf][2], 0.125f, kb4.z);
      sval[nf][3] = fmaf(sc[nf][3], 0.125f, kb4.w);
    }
    if (kt == qt) {
      int ql = wid * 16 + c;
#pragma unroll
      for (int nf = 0; nf < 4; ++nf)
#pragma unroll
        for (int r = 0; r < 4; ++r)
          if (nf * 16 + g * 4 + r > ql) sval[nf][r] = -1e9f;
    }

    // online softmax: row state is lane-local (row = c), replicated across g-groups
    float pm = sval[0][0];
#pragma unroll
    for (int nf = 0; nf < 4; ++nf)
#pragma unroll
      for (int r = 0; r < 4; ++r) pm = fmaxf(pm, sval[nf][r]);
    pm = fmaxf(pm, __shfl_xor(pm, 16));
    pm = fmaxf(pm, __shfl_xor(pm, 32));
    float mn = fmaxf(m, pm);
    float fac = __expf(m - mn);
    float p16v[4][4];
    float rs = 0.f;
#pragma unroll
    for (int nf = 0; nf < 4; ++nf)
#pragma unroll
      for (int r = 0; r < 4; ++r) {
        float pv = __expf(sval[nf][r] - mn);
        p16v[nf][r] = pv;
        rs += pv;
      }
    rs += __shfl_xor(rs, 16);
    rs += __shfl_xor(rs, 32);
    lsum = lsum * fac + rs;
    m = mn;
#pragma unroll
    for (int nf = 0; nf < 4; ++nf)
#pragma unroll
      for (int j = 0; j < 4; ++j) acc[nf][j] *= fac;

    // pack P into A-frag slot order (matches permuted V): slot j -> key 16*(j>>2)+4g+(j&3)
    bfrag pa[2];
#pragma unroll
    for (int ks = 0; ks < 2; ++ks) {
      union { u32 w[4]; bfrag f; } pu;
#pragma unroll
      for (int t = 0; t < 4; ++t)
        pu.w[t] = cvtpk(p16v[2 * ks + (t >> 1)][2 * (t & 1)],
                        p16v[2 * ks + (t >> 1)][2 * (t & 1) + 1]);
      pa[ks] = pu.f;
    }

    // PV swapped: D[dv][qrow], col=c=qrow (lane-local lsum/fac), row=g*4+j (+16nf)
#pragma unroll
    for (int nf = 0; nf < 4; ++nf) {
#pragma unroll
      for (int ks = 0; ks < 2; ++ks) {
        int row = nf * 16 + c;
        bfrag vf = *(const bfrag*)&Vs[row * 64 + ((ks * 32 + g * 8) ^ ((row & 7) << 3))];
        acc[nf] = mfma16(vf, pa[ks], acc[nf]);
      }
    }
    __syncthreads();
  }

  const float inv = 1.f / lsum;
#pragma unroll
  for (int nf = 0; nf < 4; ++nf) {
    u16x4 ov;
#pragma unroll
    for (int j = 0; j < 4; ++j) ov[j] = f2b(acc[nf][j] * inv);
    *(u16x4*)&ao[((size_t)b * S + qrow) * 1024 + h * 64 + nf * 16 + g * 4] = ov;
  }
}

// ---------------- launch ----------------
extern "C" void kernel_launch(void* const* d_in, const int* in_sizes, int n_in,
                              void* d_out, int out_size, void* d_ws, size_t ws_size,
                              hipStream_t stream)
{
  const float* Q  = (const float*)d_in[0];
  const float* Kk = (const float*)d_in[1];
  const float* V  = (const float*)d_in[2];
  const int* pad  = (const int*)d_in[3];
  const float* Wq = (const float*)d_in[4];
  const float* bq = (const float*)d_in[5];
  const float* Wk = (const float*)d_in[6];
  const float* bk = (const float*)d_in[7];
  const float* Wv = (const float*)d_in[8];
  const float* bv = (const float*)d_in[9];
  const float* Wo = (const float*)d_in[10];
  const float* bo = (const float*)d_in[11];

  // ws layout (u16 elems): 4 x WT (1M each) | q (4M) | k (4M) | v/ao (4M) | vT (4M) = 40 MiB
  u16* ws  = (u16*)d_ws;
  u16* WoT = ws + 3 * (size_t)(1u << 20);
  u16* qb  = ws + 4 * (size_t)(1u << 20);
  u16* kb  = ws + 8 * (size_t)(1u << 20);
  u16* vb  = ws + 12 * (size_t)(1u << 20);
  u16* vTb = ws + 16 * (size_t)(1u << 20);
  u16* ao  = vb;                       // v dead after vtrans+colsum; reuse for attn output
  float* colsumg = (float*)ws;         // WqT region dead after qkv_gemm (only 8 KB used)

  wtrans_kernel<<<dim3(16, 16, 4), 256, 0, stream>>>(Wq, Wk, Wv, Wo, ws);
  qkv_gemm<<<dim3(8, 32, 3), 256, 0, stream>>>(Q, Kk, V, ws, bq, bk, bv, ws);
  vtrans_kernel<<<dim3(32, 32), 256, 0, stream>>>(vb, vTb);
  colsum_kernel<<<32, 256, 0, stream>>>(vb, colsumg);
  attn_kernel<<<dim3(32, 32), 256, 0, stream>>>(qb, kb, vTb, pad, ao);
  fixup_kernel<<<2, 256, 0, stream>>>(pad, colsumg, ao);
  out_gemm<<<dim3(8, 32), 256, 0, stream>>>(ao, WoT, bo, d_out);
}

// Round 4
// 227.653 us; speedup vs baseline: 1.5015x; 1.5015x over previous
//
#include <hip/hip_runtime.h>

typedef unsigned short u16;
typedef unsigned int u32;

typedef __attribute__((ext_vector_type(8))) short bfrag;   // 8 bf16 for MFMA A/B
typedef __attribute__((ext_vector_type(4))) float f32x4;
typedef __attribute__((ext_vector_type(8))) u16 u16x8;
typedef __attribute__((ext_vector_type(4))) u16 u16x4;

constexpr int S = 2048;
constexpr int HN = 16;

__device__ __forceinline__ u16 f2b(float f) {
  u32 u = __builtin_bit_cast(u32, f);
  return (u16)((u + 0x7FFFu + ((u >> 16) & 1u)) >> 16);  // RNE f32->bf16
}
__device__ __forceinline__ float b2f(u16 v) {
  u32 u = (u32)v << 16;
  return __builtin_bit_cast(float, u);
}
__device__ __forceinline__ u32 cvtpk(float lo, float hi) {
  u32 d;
  asm("v_cvt_pk_bf16_f32 %0, %1, %2" : "=v"(d) : "v"(lo), "v"(hi));
  return d;
}

__device__ __forceinline__ f32x4 mfma16(bfrag a, bfrag b, f32x4 c) {
  return __builtin_amdgcn_mfma_f32_16x16x32_bf16(a, b, c, 0, 0, 0);
}

__device__ __forceinline__ void gload_lds16(const void* g, void* l) {
  __builtin_amdgcn_global_load_lds(
      (const __attribute__((address_space(1))) u32*)g,
      (__attribute__((address_space(3))) u32*)l, 16, 0, 0);
}

// ---------------- W transpose + f32->bf16:  WT[n][k] = (bf16) W[k][n] ----------------
__global__ __launch_bounds__(256) void wtrans_kernel(
    const float* __restrict__ W0, const float* __restrict__ W1,
    const float* __restrict__ W2, const float* __restrict__ W3,
    u16* __restrict__ ws)
{
  const float* W = blockIdx.z == 0 ? W0 : blockIdx.z == 1 ? W1 : blockIdx.z == 2 ? W2 : W3;
  u16* WT = ws + (size_t)blockIdx.z * (1u << 20);
  __shared__ u16 tile[64 * 65];
  const int t = threadIdx.x;
  const int k0 = blockIdx.y * 64, n0 = blockIdx.x * 64;
#pragma unroll
  for (int i = 0; i < 4; ++i) {
    int idx = i * 256 + t;
    int r = idx >> 4, c4 = (idx & 15) * 4;
    float4 v = *(const float4*)&W[(size_t)(k0 + r) * 1024 + n0 + c4];
    tile[r * 65 + c4 + 0] = f2b(v.x);
    tile[r * 65 + c4 + 1] = f2b(v.y);
    tile[r * 65 + c4 + 2] = f2b(v.z);
    tile[r * 65 + c4 + 3] = f2b(v.w);
  }
  __syncthreads();
#pragma unroll
  for (int i = 0; i < 2; ++i) {
    int idx = i * 256 + t;
    int n = idx >> 3, k8 = (idx & 7) * 8;
    u16x8 o;
#pragma unroll
    for (int j = 0; j < 8; ++j) o[j] = tile[(k8 + j) * 65 + n];
    *(u16x8*)&WT[(size_t)(n0 + n) * 1024 + k0 + k8] = o;
  }
}

// ------- v [B,H,S,64] -> vT [B,H,64,S] (bf16), fused column-sum (for fixup) -------
__global__ __launch_bounds__(256) void vtrans_kernel(
    const u16* __restrict__ v, u16* __restrict__ vT, float* __restrict__ colsumg)
{
  __shared__ u16 tile[64 * 65];
  const int t = threadIdx.x;
  const int s0 = blockIdx.x * 64;
  const int bh = blockIdx.y;
#pragma unroll
  for (int i = 0; i < 2; ++i) {
    int idx = i * 256 + t;
    int r = idx >> 3, c8 = (idx & 7) * 8;
    u16x8 in = *(const u16x8*)&v[((size_t)bh * S + s0 + r) * 64 + c8];
#pragma unroll
    for (int j = 0; j < 8; ++j) tile[r * 65 + c8 + j] = in[j];
  }
  __syncthreads();
#pragma unroll
  for (int i = 0; i < 2; ++i) {
    int idx = i * 256 + t;
    int d = idx >> 3, s8 = (idx & 7) * 8;
    u16x8 o;
    float psum = 0.f;
#pragma unroll
    for (int j = 0; j < 8; ++j) {
      o[j] = tile[(s8 + j) * 65 + d];
      psum += b2f(o[j]);
    }
    *(u16x8*)&vT[((size_t)bh * 64 + d) * S + s0 + s8] = o;
    // 8 lanes (s8 chunks) share one column d -> butterfly reduce, 1 atomic per column
    psum += __shfl_xor(psum, 1);
    psum += __shfl_xor(psum, 2);
    psum += __shfl_xor(psum, 4);
    if ((t & 7) == 0) atomicAdd(&colsumg[bh * 64 + d], psum);
  }
}

// ---------------- shared GEMM core: C[M,N] = A[M,K] * Bt[N,K]^T + bias ----------------
// AMODE 0: A f32 (convert to bf16 while staging); 1: A bf16.
// CMODE 0: scatter-store bf16 to [B,H,S,64]; 1: f32 linear [M,N].
template <int AMODE, int CMODE>
__device__ __forceinline__ void gemm_core(
    u16* As, u16* Bs,
    const void* __restrict__ Av, const u16* __restrict__ Bt,
    const float* __restrict__ bias, void* __restrict__ Cout,
    int N, int K, int bn, int bm)
{
  const int tid = threadIdx.x;
  const int wid = tid >> 6, lane = tid & 63;
  const int g = lane >> 4, c = lane & 15;
  const int wr = wid >> 1, wc = wid & 1;

  f32x4 acc[4][4] = {};

  const int nkt = K >> 6;
  for (int kt = 0; kt < nkt; ++kt) {
    if (AMODE == 0) {
      const float* A = (const float*)Av;
#pragma unroll
      for (int p = 0; p < 4; ++p) {
        int e = (p * 256 + tid) * 8;
        int row = e >> 6, col = e & 63;
        const float* src = &A[(size_t)(bm * 128 + row) * K + kt * 64 + col];
        float4 v0 = *(const float4*)src;
        float4 v1 = *(const float4*)(src + 4);
        u16x8 w;
        w[0] = f2b(v0.x); w[1] = f2b(v0.y); w[2] = f2b(v0.z); w[3] = f2b(v0.w);
        w[4] = f2b(v1.x); w[5] = f2b(v1.y); w[6] = f2b(v1.z); w[7] = f2b(v1.w);
        *(u16x8*)&As[row * 64 + (col ^ ((row & 7) << 3))] = w;
      }
    } else {
      const u16* A = (const u16*)Av;
#pragma unroll
      for (int p = 0; p < 4; ++p) {
        int e = (p * 256 + tid) * 8;
        int row = e >> 6, col = e & 63;
        u16x8 w = *(const u16x8*)&A[(size_t)(bm * 128 + row) * K + kt * 64 + col];
        *(u16x8*)&As[row * 64 + (col ^ ((row & 7) << 3))] = w;
      }
    }
#pragma unroll
    for (int p = 0; p < 4; ++p) {
      int off = (p * 4 + wid) * 1024 + (lane << 4);
      int row = off >> 7, colb = off & 127;
      const u16* src = &Bt[(size_t)(bn * 128 + row) * K + kt * 64 +
                           ((colb ^ ((row & 7) << 4)) >> 1)];
      gload_lds16(src, (char*)Bs + (p * 4 + wid) * 1024);
    }
    __syncthreads();

#pragma unroll
    for (int ks = 0; ks < 2; ++ks) {
      bfrag af[4], bf[4];
#pragma unroll
      for (int mi = 0; mi < 4; ++mi) {
        int row = wr * 64 + mi * 16 + c;
        af[mi] = *(const bfrag*)&As[row * 64 + ((ks * 32 + g * 8) ^ ((row & 7) << 3))];
      }
#pragma unroll
      for (int ni = 0; ni < 4; ++ni) {
        int row = wc * 64 + ni * 16 + c;
        bf[ni] = *(const bfrag*)&Bs[row * 64 + ((ks * 32 + g * 8) ^ ((row & 7) << 3))];
      }
#pragma unroll
      for (int mi = 0; mi < 4; ++mi)
#pragma unroll
        for (int ni = 0; ni < 4; ++ni)
          acc[mi][ni] = mfma16(af[mi], bf[ni], acc[mi][ni]);
    }
    __syncthreads();
  }

#pragma unroll
  for (int mi = 0; mi < 4; ++mi) {
#pragma unroll
    for (int ni = 0; ni < 4; ++ni) {
#pragma unroll
      for (int j = 0; j < 4; ++j) {
        int rowg = bm * 128 + wr * 64 + mi * 16 + g * 4 + j;
        int colg = bn * 128 + wc * 64 + ni * 16 + c;
        float val = acc[mi][ni][j] + bias[colg];
        if (CMODE == 0) {
          int b = rowg >> 11, s = rowg & (S - 1);
          int h = colg >> 6, d = colg & 63;
          ((u16*)Cout)[((size_t)((b * HN + h) * S + s)) * 64 + d] = f2b(val);
        } else {
          ((float*)Cout)[(size_t)rowg * N + colg] = val;
        }
      }
    }
  }
}

// fused Q/K/V projection: blockIdx.z selects which
__global__ __launch_bounds__(256) void qkv_gemm(
    const float* __restrict__ A0, const float* __restrict__ A1, const float* __restrict__ A2,
    const u16* __restrict__ WTbase,
    const float* __restrict__ b0, const float* __restrict__ b1, const float* __restrict__ b2,
    u16* __restrict__ wsbase)
{
  __shared__ __align__(16) u16 As[128 * 64];
  __shared__ __align__(16) u16 Bs[128 * 64];
  const int z = blockIdx.z;
  const float* A = z == 0 ? A0 : z == 1 ? A1 : A2;
  const u16* Bt = WTbase + (size_t)z * (1u << 20);
  const float* bias = z == 0 ? b0 : z == 1 ? b1 : b2;
  u16* C = wsbase + (size_t)(4 + 4 * z) * (1u << 20);
  gemm_core<0, 0>(As, Bs, A, Bt, bias, C, 1024, 1024, blockIdx.x, blockIdx.y);
}

__global__ __launch_bounds__(256) void out_gemm(
    const u16* __restrict__ Av, const u16* __restrict__ Bt,
    const float* __restrict__ bias, void* __restrict__ Cout)
{
  __shared__ __align__(16) u16 As[128 * 64];
  __shared__ __align__(16) u16 Bs[128 * 64];
  gemm_core<1, 1>(As, Bs, Av, Bt, bias, Cout, 1024, 1024, blockIdx.x, blockIdx.y);
}

// rows with all-pad causal prefix: reference softmax is uniform over ALL 2048 keys
__global__ __launch_bounds__(256) void fixup_kernel(
    const int* __restrict__ pad, const float* __restrict__ colsumg, u16* __restrict__ ao)
{
  __shared__ int fzs;
  const int tid = threadIdx.x;
  const int b = blockIdx.x;
  if (tid == 0) fzs = S;
  __syncthreads();
  int local = S;
  for (int i = tid; i < S; i += 256)
    if (pad[b * S + i] == 0) local = min(local, i);
  atomicMin(&fzs, local);
  __syncthreads();
  const int fz = fzs;
  for (int idx = tid; idx < fz * 1024; idx += 256) {
    int row = idx >> 10, col = idx & 1023;
    int h = col >> 6, d = col & 63;
    ao[((size_t)b * S + row) * 1024 + col] = f2b(colsumg[(b * 16 + h) * 64 + d] * (1.f / 2048.f));
  }
}

// ---------------- flash attention, causal tiles only, swapped-operand MFMA ----------------
// QK^T computed as mfma(K,Q) -> lane owns one q-row (c); PV as mfma(V,P) with V's key
// axis stored PERMUTED in LDS (slot = key with nf/g bitfields swapped) so P feeds MFMA
// straight from registers (no cross-lane exchange needed).
__global__ __launch_bounds__(256) void attn_kernel(
    const u16* __restrict__ q, const u16* __restrict__ k,
    const u16* __restrict__ vT, const int* __restrict__ pad,
    u16* __restrict__ ao)
{
  __shared__ __align__(16) u16 Ks[64 * 64];
  __shared__ __align__(16) u16 Vs[64 * 64];
  __shared__ __align__(16) float biasS[2048];

  const int tid = threadIdx.x;
  const int wid = tid >> 6, lane = tid & 63;
  const int g = lane >> 4, c = lane & 15;
  const int qt = blockIdx.x, bh = blockIdx.y;
  const int b = bh >> 4, h = bh & 15;

  // pad bias (read each tile as float4 broadcast)
  for (int i = tid; i < S; i += 256)
    biasS[i] = pad[b * S + i] ? -1e9f : 0.f;

  const int qrow = qt * 64 + wid * 16 + c;
  bfrag qf[2];
#pragma unroll
  for (int ks = 0; ks < 2; ++ks)
    qf[ks] = *(const bfrag*)&q[((size_t)bh * S + qrow) * 64 + ks * 32 + g * 8];

  float m = -3.0e38f, lsum = 0.f;
  f32x4 acc[4] = {};

  for (int kt = 0; kt <= qt; ++kt) {
    // stage K [64 keys][64 d] via global_load_lds, XOR-swizzled (pre-swizzled source)
#pragma unroll
    for (int p = 0; p < 2; ++p) {
      int off = (wid * 2 + p) * 1024 + (lane << 4);
      int row = off >> 7, colb = off & 127;
      gload_lds16(&k[((size_t)bh * S + kt * 64 + row) * 64 + ((colb ^ ((row & 7) << 4)) >> 1)],
                  (char*)Ks + (wid * 2 + p) * 1024);
    }
    // stage V^T [64 dv][64 keys] reg-staged, key axis permuted (slot = swap nf/g fields)
    // + XOR swizzle per dv row. key=32ks+16nf+4g+r  ->  slot=32ks+8g+4nf+r.
#pragma unroll
    for (int p = 0; p < 2; ++p) {
      int e = p * 256 + tid;
      int dv = e >> 3, key0 = (e & 7) << 3;
      u16x8 w = *(const u16x8*)&vT[((size_t)bh * 64 + dv) * S + kt * 64 + key0];
      int ks_ = key0 >> 5, nf_ = (key0 >> 4) & 1, g0 = (key0 >> 2) & 3;
      int s0 = ks_ * 32 + g0 * 8 + nf_ * 4;
      int s1 = ks_ * 32 + (g0 + 1) * 8 + nf_ * 4;
      int x = (dv & 7) << 3;
      u16x4 lo = {w[0], w[1], w[2], w[3]};
      u16x4 hi = {w[4], w[5], w[6], w[7]};
      *(u16x4*)&Vs[dv * 64 + (s0 ^ x)] = lo;
      *(u16x4*)&Vs[dv * 64 + (s1 ^ x)] = hi;
    }
    __syncthreads();

    // QK^T swapped: D[key][qrow], col=c=qrow, row=g*4+r (+16nf)
    f32x4 sc[4] = {};
#pragma unroll
    for (int ks = 0; ks < 2; ++ks) {
#pragma unroll
      for (int nf = 0; nf < 4; ++nf) {
        int row = nf * 16 + c;
        bfrag kf = *(const bfrag*)&Ks[row * 64 + ((ks * 32 + g * 8) ^ ((row & 7) << 3))];
        sc[nf] = mfma16(kf, qf[ks], sc[nf]);
      }
    }

    // mask: score = s/8 + padbias; diagonal tile adds causal
    float sval[4][4];
#pragma unroll
    for (int nf = 0; nf < 4; ++nf) {
      float4 kb4 = *(const float4*)&biasS[kt * 64 + nf * 16 + g * 4];
      sval[nf][0] = fmaf(sc[nf][0], 0.125f, kb4.x);
      sval[nf][1] = fmaf(sc[nf][1], 0.125f, kb4.y);
      sval[nf][2] = fmaf(sc[nf][2], 0.125f, kb4.z);
      sval[nf][3] = fmaf(sc[nf][3], 0.125f, kb4.w);
    }
    if (kt == qt) {
      int ql = wid * 16 + c;
#pragma unroll
      for (int nf = 0; nf < 4; ++nf)
#pragma unroll
        for (int r = 0; r < 4; ++r)
          if (nf * 16 + g * 4 + r > ql) sval[nf][r] = -1e9f;
    }

    // online softmax: row state is lane-local (row = c), replicated across g-groups
    float pm = sval[0][0];
#pragma unroll
    for (int nf = 0; nf < 4; ++nf)
#pragma unroll
      for (int r = 0; r < 4; ++r) pm = fmaxf(pm, sval[nf][r]);
    pm = fmaxf(pm, __shfl_xor(pm, 16));
    pm = fmaxf(pm, __shfl_xor(pm, 32));
    float mn = fmaxf(m, pm);
    float fac = __expf(m - mn);
    float p16v[4][4];
    float rs = 0.f;
#pragma unroll
    for (int nf = 0; nf < 4; ++nf)
#pragma unroll
      for (int r = 0; r < 4; ++r) {
        float pv = __expf(sval[nf][r] - mn);
        p16v[nf][r] = pv;
        rs += pv;
      }
    rs += __shfl_xor(rs, 16);
    rs += __shfl_xor(rs, 32);
    lsum = lsum * fac + rs;
    m = mn;
#pragma unroll
    for (int nf = 0; nf < 4; ++nf)
#pragma unroll
      for (int j = 0; j < 4; ++j) acc[nf][j] *= fac;

    // pack P into A-frag slot order (matches permuted V): slot j -> key 16*(j>>2)+4g+(j&3)
    bfrag pa[2];
#pragma unroll
    for (int ks = 0; ks < 2; ++ks) {
      union { u32 w[4]; bfrag f; } pu;
#pragma unroll
      for (int t = 0; t < 4; ++t)
        pu.w[t] = cvtpk(p16v[2 * ks + (t >> 1)][2 * (t & 1)],
                        p16v[2 * ks + (t >> 1)][2 * (t & 1) + 1]);
      pa[ks] = pu.f;
    }

    // PV swapped: D[dv][qrow], col=c=qrow (lane-local lsum/fac), row=g*4+j (+16nf)
#pragma unroll
    for (int nf = 0; nf < 4; ++nf) {
#pragma unroll
      for (int ks = 0; ks < 2; ++ks) {
        int row = nf * 16 + c;
        bfrag vf = *(const bfrag*)&Vs[row * 64 + ((ks * 32 + g * 8) ^ ((row & 7) << 3))];
        acc[nf] = mfma16(vf, pa[ks], acc[nf]);
      }
    }
    __syncthreads();
  }

  const float inv = 1.f / lsum;
#pragma unroll
  for (int nf = 0; nf < 4; ++nf) {
    u16x4 ov;
#pragma unroll
    for (int j = 0; j < 4; ++j) ov[j] = f2b(acc[nf][j] * inv);
    *(u16x4*)&ao[((size_t)b * S + qrow) * 1024 + h * 64 + nf * 16 + g * 4] = ov;
  }
}

// ---------------- launch ----------------
extern "C" void kernel_launch(void* const* d_in, const int* in_sizes, int n_in,
                              void* d_out, int out_size, void* d_ws, size_t ws_size,
                              hipStream_t stream)
{
  const float* Q  = (const float*)d_in[0];
  const float* Kk = (const float*)d_in[1];
  const float* V  = (const float*)d_in[2];
  const int* pad  = (const int*)d_in[3];
  const float* Wq = (const float*)d_in[4];
  const float* bq = (const float*)d_in[5];
  const float* Wk = (const float*)d_in[6];
  const float* bk = (const float*)d_in[7];
  const float* Wv = (const float*)d_in[8];
  const float* bv = (const float*)d_in[9];
  const float* Wo = (const float*)d_in[10];
  const float* bo = (const float*)d_in[11];

  // ws layout (u16 elems): 4 x WT (1M each) | q (4M) | k (4M) | v/ao (4M) | vT (4M) = 40 MiB
  u16* ws  = (u16*)d_ws;
  u16* WoT = ws + 3 * (size_t)(1u << 20);
  u16* qb  = ws + 4 * (size_t)(1u << 20);
  u16* kb  = ws + 8 * (size_t)(1u << 20);
  u16* vb  = ws + 12 * (size_t)(1u << 20);
  u16* vTb = ws + 16 * (size_t)(1u << 20);
  u16* ao  = vb;                       // v dead after vtrans; reuse for attn output
  float* colsumg = (float*)(ws + (1u << 20));  // WkT region dead after qkv_gemm (8 KB used)

  wtrans_kernel<<<dim3(16, 16, 4), 256, 0, stream>>>(Wq, Wk, Wv, Wo, ws);
  qkv_gemm<<<dim3(8, 32, 3), 256, 0, stream>>>(Q, Kk, V, ws, bq, bk, bv, ws);
  hipMemsetAsync(colsumg, 0, 32 * 64 * sizeof(float), stream);
  vtrans_kernel<<<dim3(32, 32), 256, 0, stream>>>(vb, vTb, colsumg);
  attn_kernel<<<dim3(32, 32), 256, 0, stream>>>(qb, kb, vTb, pad, ao);
  fixup_kernel<<<2, 256, 0, stream>>>(pad, colsumg, ao);
  out_gemm<<<dim3(8, 32), 256, 0, stream>>>(ao, WoT, bo, d_out);
}

// Round 5
// 178.744 us; speedup vs baseline: 1.9123x; 1.2736x over previous
//
#include <hip/hip_runtime.h>

typedef unsigned short u16;
typedef unsigned int u32;

typedef __attribute__((ext_vector_type(8))) short bfrag;   // 8 bf16 for MFMA A/B
typedef __attribute__((ext_vector_type(4))) float f32x4;
typedef __attribute__((ext_vector_type(8))) u16 u16x8;
typedef __attribute__((ext_vector_type(4))) u16 u16x4;

constexpr int S = 2048;
constexpr int HN = 16;

__device__ __forceinline__ u16 f2b(float f) {
  u32 u = __builtin_bit_cast(u32, f);
  return (u16)((u + 0x7FFFu + ((u >> 16) & 1u)) >> 16);  // RNE f32->bf16
}
__device__ __forceinline__ float b2f(u16 v) {
  u32 u = (u32)v << 16;
  return __builtin_bit_cast(float, u);
}
__device__ __forceinline__ u32 cvtpk(float lo, float hi) {
  u32 d;
  asm("v_cvt_pk_bf16_f32 %0, %1, %2" : "=v"(d) : "v"(lo), "v"(hi));
  return d;
}

__device__ __forceinline__ f32x4 mfma16(bfrag a, bfrag b, f32x4 c) {
  return __builtin_amdgcn_mfma_f32_16x16x32_bf16(a, b, c, 0, 0, 0);
}

__device__ __forceinline__ void gload_lds16(const void* g, void* l) {
  __builtin_amdgcn_global_load_lds(
      (const __attribute__((address_space(1))) u32*)g,
      (__attribute__((address_space(3))) u32*)l, 16, 0, 0);
}

// ---------------- W transpose + f32->bf16:  WT[n][k] = (bf16) W[k][n] ----------------
__global__ __launch_bounds__(256) void wtrans_kernel(
    const float* __restrict__ W0, const float* __restrict__ W1,
    const float* __restrict__ W2, const float* __restrict__ W3,
    u16* __restrict__ ws)
{
  const float* W = blockIdx.z == 0 ? W0 : blockIdx.z == 1 ? W1 : blockIdx.z == 2 ? W2 : W3;
  u16* WT = ws + (size_t)blockIdx.z * (1u << 20);
  __shared__ u16 tile[64 * 65];
  const int t = threadIdx.x;
  const int k0 = blockIdx.y * 64, n0 = blockIdx.x * 64;
#pragma unroll
  for (int i = 0; i < 4; ++i) {
    int idx = i * 256 + t;
    int r = idx >> 4, c4 = (idx & 15) * 4;
    float4 v = *(const float4*)&W[(size_t)(k0 + r) * 1024 + n0 + c4];
    tile[r * 65 + c4 + 0] = f2b(v.x);
    tile[r * 65 + c4 + 1] = f2b(v.y);
    tile[r * 65 + c4 + 2] = f2b(v.z);
    tile[r * 65 + c4 + 3] = f2b(v.w);
  }
  __syncthreads();
#pragma unroll
  for (int i = 0; i < 2; ++i) {
    int idx = i * 256 + t;
    int n = idx >> 3, k8 = (idx & 7) * 8;
    u16x8 o;
#pragma unroll
    for (int j = 0; j < 8; ++j) o[j] = tile[(k8 + j) * 65 + n];
    *(u16x8*)&WT[(size_t)(n0 + n) * 1024 + k0 + k8] = o;
  }
}

// ------- v [B,H,S,64] -> vT [B,H,64,S] (bf16), fused column-sum (for fixup) -------
__global__ __launch_bounds__(256) void vtrans_kernel(
    const u16* __restrict__ v, u16* __restrict__ vT, float* __restrict__ colsumg)
{
  __shared__ u16 tile[64 * 65];
  const int t = threadIdx.x;
  const int s0 = blockIdx.x * 64;
  const int bh = blockIdx.y;
#pragma unroll
  for (int i = 0; i < 2; ++i) {
    int idx = i * 256 + t;
    int r = idx >> 3, c8 = (idx & 7) * 8;
    u16x8 in = *(const u16x8*)&v[((size_t)bh * S + s0 + r) * 64 + c8];
#pragma unroll
    for (int j = 0; j < 8; ++j) tile[r * 65 + c8 + j] = in[j];
  }
  __syncthreads();
#pragma unroll
  for (int i = 0; i < 2; ++i) {
    int idx = i * 256 + t;
    int d = idx >> 3, s8 = (idx & 7) * 8;
    u16x8 o;
    float psum = 0.f;
#pragma unroll
    for (int j = 0; j < 8; ++j) {
      o[j] = tile[(s8 + j) * 65 + d];
      psum += b2f(o[j]);
    }
    *(u16x8*)&vT[((size_t)bh * 64 + d) * S + s0 + s8] = o;
    // 8 lanes (s8 chunks) share one column d -> butterfly reduce, 1 atomic per column
    psum += __shfl_xor(psum, 1);
    psum += __shfl_xor(psum, 2);
    psum += __shfl_xor(psum, 4);
    if ((t & 7) == 0) atomicAdd(&colsumg[bh * 64 + d], psum);
  }
}

// ---------------- shared GEMM core: C[M,N] = A[M,K] * Bt[N,K]^T + bias ----------------
// AMODE 0: A f32 (convert to bf16 while staging); 1: A bf16.
// CMODE 0: scatter-store bf16 to [B,H,S,64]; 1: f32 linear [M,N].
template <int AMODE, int CMODE>
__device__ __forceinline__ void gemm_core(
    u16* As, u16* Bs,
    const void* __restrict__ Av, const u16* __restrict__ Bt,
    const float* __restrict__ bias, void* __restrict__ Cout,
    int N, int K, int bn, int bm)
{
  const int tid = threadIdx.x;
  const int wid = tid >> 6, lane = tid & 63;
  const int g = lane >> 4, c = lane & 15;
  const int wr = wid >> 1, wc = wid & 1;

  f32x4 acc[4][4] = {};

  const int nkt = K >> 6;
  for (int kt = 0; kt < nkt; ++kt) {
    if (AMODE == 0) {
      const float* A = (const float*)Av;
#pragma unroll
      for (int p = 0; p < 4; ++p) {
        int e = (p * 256 + tid) * 8;
        int row = e >> 6, col = e & 63;
        const float* src = &A[(size_t)(bm * 128 + row) * K + kt * 64 + col];
        float4 v0 = *(const float4*)src;
        float4 v1 = *(const float4*)(src + 4);
        u16x8 w;
        w[0] = f2b(v0.x); w[1] = f2b(v0.y); w[2] = f2b(v0.z); w[3] = f2b(v0.w);
        w[4] = f2b(v1.x); w[5] = f2b(v1.y); w[6] = f2b(v1.z); w[7] = f2b(v1.w);
        *(u16x8*)&As[row * 64 + (col ^ ((row & 7) << 3))] = w;
      }
    } else {
      const u16* A = (const u16*)Av;
#pragma unroll
      for (int p = 0; p < 4; ++p) {
        int e = (p * 256 + tid) * 8;
        int row = e >> 6, col = e & 63;
        u16x8 w = *(const u16x8*)&A[(size_t)(bm * 128 + row) * K + kt * 64 + col];
        *(u16x8*)&As[row * 64 + (col ^ ((row & 7) << 3))] = w;
      }
    }
#pragma unroll
    for (int p = 0; p < 4; ++p) {
      int off = (p * 4 + wid) * 1024 + (lane << 4);
      int row = off >> 7, colb = off & 127;
      const u16* src = &Bt[(size_t)(bn * 128 + row) * K + kt * 64 +
                           ((colb ^ ((row & 7) << 4)) >> 1)];
      gload_lds16(src, (char*)Bs + (p * 4 + wid) * 1024);
    }
    __syncthreads();

#pragma unroll
    for (int ks = 0; ks < 2; ++ks) {
      bfrag af[4], bf[4];
#pragma unroll
      for (int mi = 0; mi < 4; ++mi) {
        int row = wr * 64 + mi * 16 + c;
        af[mi] = *(const bfrag*)&As[row * 64 + ((ks * 32 + g * 8) ^ ((row & 7) << 3))];
      }
#pragma unroll
      for (int ni = 0; ni < 4; ++ni) {
        int row = wc * 64 + ni * 16 + c;
        bf[ni] = *(const bfrag*)&Bs[row * 64 + ((ks * 32 + g * 8) ^ ((row & 7) << 3))];
      }
#pragma unroll
      for (int mi = 0; mi < 4; ++mi)
#pragma unroll
        for (int ni = 0; ni < 4; ++ni)
          acc[mi][ni] = mfma16(af[mi], bf[ni], acc[mi][ni]);
    }
    __syncthreads();
  }

#pragma unroll
  for (int mi = 0; mi < 4; ++mi) {
#pragma unroll
    for (int ni = 0; ni < 4; ++ni) {
#pragma unroll
      for (int j = 0; j < 4; ++j) {
        int rowg = bm * 128 + wr * 64 + mi * 16 + g * 4 + j;
        int colg = bn * 128 + wc * 64 + ni * 16 + c;
        float val = acc[mi][ni][j] + bias[colg];
        if (CMODE == 0) {
          int b = rowg >> 11, s = rowg & (S - 1);
          int h = colg >> 6, d = colg & 63;
          ((u16*)Cout)[((size_t)((b * HN + h) * S + s)) * 64 + d] = f2b(val);
        } else {
          ((float*)Cout)[(size_t)rowg * N + colg] = val;
        }
      }
    }
  }
}

// fused Q/K/V projection: blockIdx.z selects which
__global__ __launch_bounds__(256) void qkv_gemm(
    const float* __restrict__ A0, const float* __restrict__ A1, const float* __restrict__ A2,
    const u16* __restrict__ WTbase,
    const float* __restrict__ b0, const float* __restrict__ b1, const float* __restrict__ b2,
    u16* __restrict__ wsbase)
{
  __shared__ __align__(16) u16 As[128 * 64];
  __shared__ __align__(16) u16 Bs[128 * 64];
  const int z = blockIdx.z;
  const float* A = z == 0 ? A0 : z == 1 ? A1 : A2;
  const u16* Bt = WTbase + (size_t)z * (1u << 20);
  const float* bias = z == 0 ? b0 : z == 1 ? b1 : b2;
  u16* C = wsbase + (size_t)(4 + 4 * z) * (1u << 20);
  gemm_core<0, 0>(As, Bs, A, Bt, bias, C, 1024, 1024, blockIdx.x, blockIdx.y);
}

__global__ __launch_bounds__(256) void out_gemm(
    const u16* __restrict__ Av, const u16* __restrict__ Bt,
    const float* __restrict__ bias, void* __restrict__ Cout)
{
  __shared__ __align__(16) u16 As[128 * 64];
  __shared__ __align__(16) u16 Bs[128 * 64];
  gemm_core<1, 1>(As, Bs, Av, Bt, bias, Cout, 1024, 1024, blockIdx.x, blockIdx.y);
}

// rows with all-pad causal prefix: reference softmax is uniform over ALL 2048 keys
__global__ __launch_bounds__(256) void fixup_kernel(
    const int* __restrict__ pad, const float* __restrict__ colsumg, u16* __restrict__ ao)
{
  __shared__ int fzs;
  const int tid = threadIdx.x;
  const int b = blockIdx.x;
  if (tid == 0) fzs = S;
  __syncthreads();
  int local = S;
  for (int i = tid; i < S; i += 256)
    if (pad[b * S + i] == 0) local = min(local, i);
  atomicMin(&fzs, local);
  __syncthreads();
  const int fz = fzs;
  for (int idx = tid; idx < fz * 1024; idx += 256) {
    int row = idx >> 10, col = idx & 1023;
    int h = col >> 6, d = col & 63;
    ao[((size_t)b * S + row) * 1024 + col] = f2b(colsumg[(b * 16 + h) * 64 + d] * (1.f / 2048.f));
  }
}

// ---------------- flash attention v2 ----------------
// QBLK=128 (4 waves x 32 q-rows, 2 fragments each), KVBLK=64, double-buffered K/V,
// async prefetch (K via global_load_lds, V via reg-stage), defer-max softmax,
// paired q-tiles (qt, 15-qt) for exact load balance, XCD-affine bh mapping.
__global__ __launch_bounds__(256) void attn_kernel(
    const u16* __restrict__ q, const u16* __restrict__ k,
    const u16* __restrict__ vT, const int* __restrict__ pad,
    u16* __restrict__ ao)
{
  __shared__ __align__(16) u16 Ks[2][64 * 64];
  __shared__ __align__(16) u16 Vs[2][64 * 64];
  __shared__ __align__(16) float biasS[2048];

  const int tid = threadIdx.x;
  const int wid = tid >> 6, lane = tid & 63;
  const int g = lane >> 4, c = lane & 15;
  const int bid = blockIdx.x;
  const int bh = (bid & 7) | ((bid >> 6) << 3);   // all 8 pair-blocks of a bh on one XCD
  const int pairi = (bid >> 3) & 7;
  const int b = bh >> 4, h = bh & 15;

  for (int i = tid; i < S; i += 256)
    biasS[i] = pad[b * S + i] ? -1e9f : 0.f;

  for (int pass = 0; pass < 2; ++pass) {
    const int qt = pass == 0 ? pairi : 15 - pairi;
    const int nt = 2 * qt + 2;
    const int qbase = qt * 128 + wid * 32;

    bfrag qf[2][2];
#pragma unroll
    for (int u = 0; u < 2; ++u)
#pragma unroll
      for (int ks = 0; ks < 2; ++ks)
        qf[u][ks] = *(const bfrag*)&q[((size_t)bh * S + qbase + u * 16 + c) * 64 + ks * 32 + g * 8];

    float m[2] = {-3.0e38f, -3.0e38f};
    float lsum[2] = {0.f, 0.f};
    f32x4 acc[2][4] = {};

    // ---- prologue: stage tile 0 into buffer 0 ----
    u16x8 vr[2];
#pragma unroll
    for (int p = 0; p < 2; ++p) {
      int off = (wid * 2 + p) * 1024 + (lane << 4);
      int row = off >> 7, colb = off & 127;
      gload_lds16(&k[((size_t)bh * S + row) * 64 + ((colb ^ ((row & 7) << 4)) >> 1)],
                  (char*)Ks[0] + (wid * 2 + p) * 1024);
    }
#pragma unroll
    for (int p = 0; p < 2; ++p) {
      int e = p * 256 + tid;
      int dv = e >> 3, key0 = (e & 7) << 3;
      vr[p] = *(const u16x8*)&vT[((size_t)bh * 64 + dv) * S + key0];
    }
#pragma unroll
    for (int p = 0; p < 2; ++p) {
      int e = p * 256 + tid;
      int dv = e >> 3, key0 = (e & 7) << 3;
      int ks_ = key0 >> 5, nf_ = (key0 >> 4) & 1, g0 = (key0 >> 2) & 3;
      int s0 = ks_ * 32 + g0 * 8 + nf_ * 4;
      int s1 = ks_ * 32 + (g0 + 1) * 8 + nf_ * 4;
      int x = (dv & 7) << 3;
      u16x4 lo = {vr[p][0], vr[p][1], vr[p][2], vr[p][3]};
      u16x4 hi = {vr[p][4], vr[p][5], vr[p][6], vr[p][7]};
      *(u16x4*)&Vs[0][dv * 64 + (s0 ^ x)] = lo;
      *(u16x4*)&Vs[0][dv * 64 + (s1 ^ x)] = hi;
    }
    __syncthreads();

    int cur = 0;
    for (int t = 0; t < nt; ++t) {
      const bool pre = (t + 1 < nt);
      if (pre) {
        // async prefetch tile t+1: K -> LDS buf^1, V -> regs
#pragma unroll
        for (int p = 0; p < 2; ++p) {
          int off = (wid * 2 + p) * 1024 + (lane << 4);
          int row = off >> 7, colb = off & 127;
          gload_lds16(&k[((size_t)bh * S + (t + 1) * 64 + row) * 64 + ((colb ^ ((row & 7) << 4)) >> 1)],
                      (char*)Ks[cur ^ 1] + (wid * 2 + p) * 1024);
        }
#pragma unroll
        for (int p = 0; p < 2; ++p) {
          int e = p * 256 + tid;
          int dv = e >> 3, key0 = (e & 7) << 3;
          vr[p] = *(const u16x8*)&vT[((size_t)bh * 64 + dv) * S + (t + 1) * 64 + key0];
        }
      }

      // ---- QK^T (swapped): D[key][qrow], both q-fragments share K fragments ----
      bfrag kfr[2][4];
#pragma unroll
      for (int ks = 0; ks < 2; ++ks)
#pragma unroll
        for (int nf = 0; nf < 4; ++nf) {
          int row = nf * 16 + c;
          kfr[ks][nf] = *(const bfrag*)&Ks[cur][row * 64 + ((ks * 32 + g * 8) ^ ((row & 7) << 3))];
        }
      f32x4 sc[2][4] = {};
#pragma unroll
      for (int u = 0; u < 2; ++u)
#pragma unroll
        for (int ks = 0; ks < 2; ++ks)
#pragma unroll
          for (int nf = 0; nf < 4; ++nf)
            sc[u][nf] = mfma16(kfr[ks][nf], qf[u][ks], sc[u][nf]);

      float4 kb[4];
#pragma unroll
      for (int nf = 0; nf < 4; ++nf)
        kb[nf] = *(const float4*)&biasS[t * 64 + nf * 16 + g * 4];

      // ---- softmax per q-fragment (lane-local rows, defer-max) ----
      bfrag pa[2][2];
#pragma unroll
      for (int u = 0; u < 2; ++u) {
        float sval[4][4];
#pragma unroll
        for (int nf = 0; nf < 4; ++nf) {
          sval[nf][0] = fmaf(sc[u][nf][0], 0.125f, kb[nf].x);
          sval[nf][1] = fmaf(sc[u][nf][1], 0.125f, kb[nf].y);
          sval[nf][2] = fmaf(sc[u][nf][2], 0.125f, kb[nf].z);
          sval[nf][3] = fmaf(sc[u][nf][3], 0.125f, kb[nf].w);
        }
        if (t * 64 + 63 > qbase + u * 16) {  // causal masking can affect this fragment
          int qrow_g = qbase + u * 16 + c;
#pragma unroll
          for (int nf = 0; nf < 4; ++nf)
#pragma unroll
            for (int r = 0; r < 4; ++r)
              if (t * 64 + nf * 16 + g * 4 + r > qrow_g) sval[nf][r] = -1e9f;
        }
        float pm = sval[0][0];
#pragma unroll
        for (int nf = 0; nf < 4; ++nf)
#pragma unroll
          for (int r = 0; r < 4; ++r) pm = fmaxf(pm, sval[nf][r]);
        pm = fmaxf(pm, __shfl_xor(pm, 16));
        pm = fmaxf(pm, __shfl_xor(pm, 32));
        if (!__all(pm - m[u] <= 8.f)) {   // defer-max: rescale only when max grew
          float mn = fmaxf(m[u], pm);
          float fac = __expf(m[u] - mn);
          lsum[u] *= fac;
#pragma unroll
          for (int nf = 0; nf < 4; ++nf)
#pragma unroll
            for (int j = 0; j < 4; ++j) acc[u][nf][j] *= fac;
          m[u] = mn;
        }
        float p16v[4][4];
        float rs = 0.f;
#pragma unroll
        for (int nf = 0; nf < 4; ++nf)
#pragma unroll
          for (int r = 0; r < 4; ++r) {
            float pv = __expf(sval[nf][r] - m[u]);
            p16v[nf][r] = pv;
            rs += pv;
          }
        rs += __shfl_xor(rs, 16);
        rs += __shfl_xor(rs, 32);
        lsum[u] += rs;
        // pack P into A-frag slot order (matches permuted V)
#pragma unroll
        for (int ks = 0; ks < 2; ++ks) {
          union { u32 w[4]; bfrag f; } pu;
#pragma unroll
          for (int tt = 0; tt < 4; ++tt)
            pu.w[tt] = cvtpk(p16v[2 * ks + (tt >> 1)][2 * (tt & 1)],
                             p16v[2 * ks + (tt >> 1)][2 * (tt & 1) + 1]);
          pa[u][ks] = pu.f;
        }
      }

      // ---- PV (swapped): D[dv][qrow], V fragments shared across q-fragments ----
      bfrag vfr[2][4];
#pragma unroll
      for (int ks = 0; ks < 2; ++ks)
#pragma unroll
        for (int nf = 0; nf < 4; ++nf) {
          int row = nf * 16 + c;
          vfr[ks][nf] = *(const bfrag*)&Vs[cur][row * 64 + ((ks * 32 + g * 8) ^ ((row & 7) << 3))];
        }
#pragma unroll
      for (int u = 0; u < 2; ++u)
#pragma unroll
        for (int ks = 0; ks < 2; ++ks)
#pragma unroll
          for (int nf = 0; nf < 4; ++nf)
            acc[u][nf] = mfma16(vfr[ks][nf], pa[u][ks], acc[u][nf]);

      if (pre) {
        // write prefetched V regs into buf^1 (compiler waits vmcnt for vr)
#pragma unroll
        for (int p = 0; p < 2; ++p) {
          int e = p * 256 + tid;
          int dv = e >> 3, key0 = (e & 7) << 3;
          int ks_ = key0 >> 5, nf_ = (key0 >> 4) & 1, g0 = (key0 >> 2) & 3;
          int s0 = ks_ * 32 + g0 * 8 + nf_ * 4;
          int s1 = ks_ * 32 + (g0 + 1) * 8 + nf_ * 4;
          int x = (dv & 7) << 3;
          u16x4 lo = {vr[p][0], vr[p][1], vr[p][2], vr[p][3]};
          u16x4 hi = {vr[p][4], vr[p][5], vr[p][6], vr[p][7]};
          *(u16x4*)&Vs[cur ^ 1][dv * 64 + (s0 ^ x)] = lo;
          *(u16x4*)&Vs[cur ^ 1][dv * 64 + (s1 ^ x)] = hi;
        }
      }
      __syncthreads();
      cur ^= 1;
    }

    // ---- epilogue ----
#pragma unroll
    for (int u = 0; u < 2; ++u) {
      const float inv = 1.f / lsum[u];
      const int qrow = qbase + u * 16 + c;
#pragma unroll
      for (int nf = 0; nf < 4; ++nf) {
        u16x4 ov;
#pragma unroll
        for (int j = 0; j < 4; ++j) ov[j] = f2b(acc[u][nf][j] * inv);
        *(u16x4*)&ao[((size_t)b * S + qrow) * 1024 + h * 64 + nf * 16 + g * 4] = ov;
      }
    }
  }
}

// ---------------- launch ----------------
extern "C" void kernel_launch(void* const* d_in, const int* in_sizes, int n_in,
                              void* d_out, int out_size, void* d_ws, size_t ws_size,
                              hipStream_t stream)
{
  const float* Q  = (const float*)d_in[0];
  const float* Kk = (const float*)d_in[1];
  const float* V  = (const float*)d_in[2];
  const int* pad  = (const int*)d_in[3];
  const float* Wq = (const float*)d_in[4];
  const float* bq = (const float*)d_in[5];
  const float* Wk = (const float*)d_in[6];
  const float* bk = (const float*)d_in[7];
  const float* Wv = (const float*)d_in[8];
  const float* bv = (const float*)d_in[9];
  const float* Wo = (const float*)d_in[10];
  const float* bo = (const float*)d_in[11];

  // ws layout (u16 elems): 4 x WT (1M each) | q (4M) | k (4M) | v/ao (4M) | vT (4M) = 40 MiB
  u16* ws  = (u16*)d_ws;
  u16* WoT = ws + 3 * (size_t)(1u << 20);
  u16* qb  = ws + 4 * (size_t)(1u << 20);
  u16* kb  = ws + 8 * (size_t)(1u << 20);
  u16* vb  = ws + 12 * (size_t)(1u << 20);
  u16* vTb = ws + 16 * (size_t)(1u << 20);
  u16* ao  = vb;                       // v dead after vtrans; reuse for attn output
  float* colsumg = (float*)(ws + (1u << 20));  // WkT region dead after qkv_gemm (8 KB used)

  wtrans_kernel<<<dim3(16, 16, 4), 256, 0, stream>>>(Wq, Wk, Wv, Wo, ws);
  qkv_gemm<<<dim3(8, 32, 3), 256, 0, stream>>>(Q, Kk, V, ws, bq, bk, bv, ws);
  hipMemsetAsync(colsumg, 0, 32 * 64 * sizeof(float), stream);
  vtrans_kernel<<<dim3(32, 32), 256, 0, stream>>>(vb, vTb, colsumg);
  attn_kernel<<<256, 256, 0, stream>>>(qb, kb, vTb, pad, ao);
  fixup_kernel<<<2, 256, 0, stream>>>(pad, colsumg, ao);
  out_gemm<<<dim3(8, 32), 256, 0, stream>>>(ao, WoT, bo, d_out);
}

// Round 6
// 154.165 us; speedup vs baseline: 2.2172x; 1.1594x over previous
//
#include <hip/hip_runtime.h>

typedef unsigned short u16;
typedef unsigned int u32;

typedef __attribute__((ext_vector_type(8))) short bfrag;   // 8 bf16 for MFMA A/B
typedef __attribute__((ext_vector_type(4))) float f32x4;
typedef __attribute__((ext_vector_type(8))) u16 u16x8;
typedef __attribute__((ext_vector_type(4))) u16 u16x4;

constexpr int S = 2048;
constexpr int HN = 16;

__device__ __forceinline__ u16 f2b(float f) {
  u32 u = __builtin_bit_cast(u32, f);
  return (u16)((u + 0x7FFFu + ((u >> 16) & 1u)) >> 16);  // RNE f32->bf16
}
__device__ __forceinline__ float b2f(u16 v) {
  u32 u = (u32)v << 16;
  return __builtin_bit_cast(float, u);
}
__device__ __forceinline__ u32 cvtpk(float lo, float hi) {
  u32 d;
  asm("v_cvt_pk_bf16_f32 %0, %1, %2" : "=v"(d) : "v"(lo), "v"(hi));
  return d;
}

__device__ __forceinline__ f32x4 mfma16(bfrag a, bfrag b, f32x4 c) {
  return __builtin_amdgcn_mfma_f32_16x16x32_bf16(a, b, c, 0, 0, 0);
}

__device__ __forceinline__ void gload_lds16(const void* g, void* l) {
  __builtin_amdgcn_global_load_lds(
      (const __attribute__((address_space(1))) u32*)g,
      (__attribute__((address_space(3))) u32*)l, 16, 0, 0);
}

// ---------------- W transpose + f32->bf16:  WT[n][k] = (bf16) W[k][n] ----------------
__global__ __launch_bounds__(256) void wtrans_kernel(
    const float* __restrict__ W0, const float* __restrict__ W1,
    const float* __restrict__ W2, const float* __restrict__ W3,
    u16* __restrict__ ws)
{
  const float* W = blockIdx.z == 0 ? W0 : blockIdx.z == 1 ? W1 : blockIdx.z == 2 ? W2 : W3;
  u16* WT = ws + (size_t)blockIdx.z * (1u << 20);
  __shared__ u16 tile[64 * 65];
  const int t = threadIdx.x;
  const int k0 = blockIdx.y * 64, n0 = blockIdx.x * 64;
#pragma unroll
  for (int i = 0; i < 4; ++i) {
    int idx = i * 256 + t;
    int r = idx >> 4, c4 = (idx & 15) * 4;
    float4 v = *(const float4*)&W[(size_t)(k0 + r) * 1024 + n0 + c4];
    tile[r * 65 + c4 + 0] = f2b(v.x);
    tile[r * 65 + c4 + 1] = f2b(v.y);
    tile[r * 65 + c4 + 2] = f2b(v.z);
    tile[r * 65 + c4 + 3] = f2b(v.w);
  }
  __syncthreads();
#pragma unroll
  for (int i = 0; i < 2; ++i) {
    int idx = i * 256 + t;
    int n = idx >> 3, k8 = (idx & 7) * 8;
    u16x8 o;
#pragma unroll
    for (int j = 0; j < 8; ++j) o[j] = tile[(k8 + j) * 65 + n];
    *(u16x8*)&WT[(size_t)(n0 + n) * 1024 + k0 + k8] = o;
  }
}

// ---------------- f32 -> bf16 bulk convert (Q, K, V inputs) ----------------
__global__ __launch_bounds__(256) void cvt_kernel(
    const float* __restrict__ A0, const float* __restrict__ A1,
    const float* __restrict__ A2, u16* __restrict__ outbase)
{
  const float* A = blockIdx.y == 0 ? A0 : blockIdx.y == 1 ? A1 : A2;
  u16* dst = outbase + (size_t)blockIdx.y * (4u << 20);
  size_t i = ((size_t)blockIdx.x * 256 + threadIdx.x) * 8;
  float4 v0 = *(const float4*)&A[i];
  float4 v1 = *(const float4*)&A[i + 4];
  union { u32 w[4]; u16x8 v; } o;
  o.w[0] = cvtpk(v0.x, v0.y); o.w[1] = cvtpk(v0.z, v0.w);
  o.w[2] = cvtpk(v1.x, v1.y); o.w[3] = cvtpk(v1.z, v1.w);
  *(u16x8*)&dst[i] = o.v;
}

// ------- v [B,H,S,64] -> vT [B,H,64,S] (bf16), fused column-sum (for fixup) -------
__global__ __launch_bounds__(256) void vtrans_kernel(
    const u16* __restrict__ v, u16* __restrict__ vT, float* __restrict__ colsumg)
{
  __shared__ u16 tile[64 * 65];
  const int t = threadIdx.x;
  const int s0 = blockIdx.x * 64;
  const int bh = blockIdx.y;
#pragma unroll
  for (int i = 0; i < 2; ++i) {
    int idx = i * 256 + t;
    int r = idx >> 3, c8 = (idx & 7) * 8;
    u16x8 in = *(const u16x8*)&v[((size_t)bh * S + s0 + r) * 64 + c8];
#pragma unroll
    for (int j = 0; j < 8; ++j) tile[r * 65 + c8 + j] = in[j];
  }
  __syncthreads();
#pragma unroll
  for (int i = 0; i < 2; ++i) {
    int idx = i * 256 + t;
    int d = idx >> 3, s8 = (idx & 7) * 8;
    u16x8 o;
    float psum = 0.f;
#pragma unroll
    for (int j = 0; j < 8; ++j) {
      o[j] = tile[(s8 + j) * 65 + d];
      psum += b2f(o[j]);
    }
    *(u16x8*)&vT[((size_t)bh * 64 + d) * S + s0 + s8] = o;
    psum += __shfl_xor(psum, 1);
    psum += __shfl_xor(psum, 2);
    psum += __shfl_xor(psum, 4);
    if ((t & 7) == 0) atomicAdd(&colsumg[bh * 64 + d], psum);
  }
}

// ---------------- shared GEMM core: C[M,N] = A[M,K] * Bt[N,K]^T + bias ----------------
// AMODE 0: A f32 reg-staged (convert to bf16); 2: A bf16 via global_load_lds.
// CMODE 0: scatter-store bf16 to [B,H,S,64]; 1: f32 linear [M,N].
template <int AMODE, int CMODE>
__device__ __forceinline__ void gemm_core(
    u16* As, u16* Bs,
    const void* __restrict__ Av, const u16* __restrict__ Bt,
    const float* __restrict__ bias, void* __restrict__ Cout,
    int N, int K, int bn, int bm)
{
  const int tid = threadIdx.x;
  const int wid = tid >> 6, lane = tid & 63;
  const int g = lane >> 4, c = lane & 15;
  const int wr = wid >> 1, wc = wid & 1;

  f32x4 acc[4][4] = {};

  const int nkt = K >> 6;
  for (int kt = 0; kt < nkt; ++kt) {
    if (AMODE == 0) {
      const float* A = (const float*)Av;
#pragma unroll
      for (int p = 0; p < 4; ++p) {
        int e = (p * 256 + tid) * 8;
        int row = e >> 6, col = e & 63;
        const float* src = &A[(size_t)(bm * 128 + row) * K + kt * 64 + col];
        float4 v0 = *(const float4*)src;
        float4 v1 = *(const float4*)(src + 4);
        u16x8 w;
        w[0] = f2b(v0.x); w[1] = f2b(v0.y); w[2] = f2b(v0.z); w[3] = f2b(v0.w);
        w[4] = f2b(v1.x); w[5] = f2b(v1.y); w[6] = f2b(v1.z); w[7] = f2b(v1.w);
        *(u16x8*)&As[row * 64 + (col ^ ((row & 7) << 3))] = w;
      }
    } else {
      const u16* A = (const u16*)Av;
#pragma unroll
      for (int p = 0; p < 4; ++p) {
        int off = (p * 4 + wid) * 1024 + (lane << 4);
        int row = off >> 7, colb = off & 127;
        gload_lds16(&A[(size_t)(bm * 128 + row) * K + kt * 64 +
                       ((colb ^ ((row & 7) << 4)) >> 1)],
                    (char*)As + (p * 4 + wid) * 1024);
      }
    }
#pragma unroll
    for (int p = 0; p < 4; ++p) {
      int off = (p * 4 + wid) * 1024 + (lane << 4);
      int row = off >> 7, colb = off & 127;
      gload_lds16(&Bt[(size_t)(bn * 128 + row) * K + kt * 64 +
                      ((colb ^ ((row & 7) << 4)) >> 1)],
                  (char*)Bs + (p * 4 + wid) * 1024);
    }
    __syncthreads();

#pragma unroll
    for (int ks = 0; ks < 2; ++ks) {
      bfrag af[4], bf[4];
#pragma unroll
      for (int mi = 0; mi < 4; ++mi) {
        int row = wr * 64 + mi * 16 + c;
        af[mi] = *(const bfrag*)&As[row * 64 + ((ks * 32 + g * 8) ^ ((row & 7) << 3))];
      }
#pragma unroll
      for (int ni = 0; ni < 4; ++ni) {
        int row = wc * 64 + ni * 16 + c;
        bf[ni] = *(const bfrag*)&Bs[row * 64 + ((ks * 32 + g * 8) ^ ((row & 7) << 3))];
      }
#pragma unroll
      for (int mi = 0; mi < 4; ++mi)
#pragma unroll
        for (int ni = 0; ni < 4; ++ni)
          acc[mi][ni] = mfma16(af[mi], bf[ni], acc[mi][ni]);
    }
    __syncthreads();
  }

#pragma unroll
  for (int mi = 0; mi < 4; ++mi) {
#pragma unroll
    for (int ni = 0; ni < 4; ++ni) {
#pragma unroll
      for (int j = 0; j < 4; ++j) {
        int rowg = bm * 128 + wr * 64 + mi * 16 + g * 4 + j;
        int colg = bn * 128 + wc * 64 + ni * 16 + c;
        float val = acc[mi][ni][j] + bias[colg];
        if (CMODE == 0) {
          int b = rowg >> 11, s = rowg & (S - 1);
          int h = colg >> 6, d = colg & 63;
          ((u16*)Cout)[((size_t)((b * HN + h) * S + s)) * 64 + d] = f2b(val);
        } else {
          ((float*)Cout)[(size_t)rowg * N + colg] = val;
        }
      }
    }
  }
}

// pure-bf16 QKV projection, 1D grid 768, XCD-chunked decode
__global__ __launch_bounds__(256) void qkv_gemm_b16(
    const u16* __restrict__ Abase, const u16* __restrict__ WTbase,
    const float* __restrict__ b0, const float* __restrict__ b1, const float* __restrict__ b2,
    u16* __restrict__ wsbase)
{
  __shared__ __align__(16) u16 As[128 * 64];
  __shared__ __align__(16) u16 Bs[128 * 64];
  const int bid = blockIdx.x;
  const int l = (bid & 7) * 96 + (bid >> 3);   // XCD-chunked: each XCD owns 96 contiguous
  const int z = l >> 8, rem = l & 255, bm = rem >> 3, bn = rem & 7;
  const u16* A = Abase + (size_t)z * (4u << 20);
  const u16* Bt = WTbase + (size_t)z * (1u << 20);
  const float* bias = z == 0 ? b0 : z == 1 ? b1 : b2;
  u16* C = wsbase + (size_t)(4 + 4 * z) * (1u << 20);
  gemm_core<2, 0>(As, Bs, A, Bt, bias, C, 1024, 1024, bn, bm);
}

// fallback (small ws): f32-A projection, z-grid
__global__ __launch_bounds__(256) void qkv_gemm_f32(
    const float* __restrict__ A0, const float* __restrict__ A1, const float* __restrict__ A2,
    const u16* __restrict__ WTbase,
    const float* __restrict__ b0, const float* __restrict__ b1, const float* __restrict__ b2,
    u16* __restrict__ wsbase)
{
  __shared__ __align__(16) u16 As[128 * 64];
  __shared__ __align__(16) u16 Bs[128 * 64];
  const int z = blockIdx.z;
  const float* A = z == 0 ? A0 : z == 1 ? A1 : A2;
  const u16* Bt = WTbase + (size_t)z * (1u << 20);
  const float* bias = z == 0 ? b0 : z == 1 ? b1 : b2;
  u16* C = wsbase + (size_t)(4 + 4 * z) * (1u << 20);
  gemm_core<0, 0>(As, Bs, A, Bt, bias, C, 1024, 1024, blockIdx.x, blockIdx.y);
}

__global__ __launch_bounds__(256) void out_gemm(
    const u16* __restrict__ Av, const u16* __restrict__ Bt,
    const float* __restrict__ bias, void* __restrict__ Cout)
{
  __shared__ __align__(16) u16 As[128 * 64];
  __shared__ __align__(16) u16 Bs[128 * 64];
  const int bid = blockIdx.x;
  const int l = (bid & 7) * 32 + (bid >> 3);   // XCD-chunked
  const int bm = l >> 3, bn = l & 7;
  gemm_core<2, 1>(As, Bs, Av, Bt, bias, Cout, 1024, 1024, bn, bm);
}

// rows with all-pad causal prefix: reference softmax is uniform over ALL 2048 keys
__global__ __launch_bounds__(256) void fixup_kernel(
    const int* __restrict__ pad, const float* __restrict__ colsumg, u16* __restrict__ ao)
{
  __shared__ int fzs;
  const int tid = threadIdx.x;
  const int b = blockIdx.x;
  if (tid == 0) fzs = S;
  __syncthreads();
  int local = S;
  for (int i = tid; i < S; i += 256)
    if (pad[b * S + i] == 0) local = min(local, i);
  atomicMin(&fzs, local);
  __syncthreads();
  const int fz = fzs;
  for (int idx = tid; idx < fz * 1024; idx += 256) {
    int row = idx >> 10, col = idx & 1023;
    int h = col >> 6, d = col & 63;
    ao[((size_t)b * S + row) * 1024 + col] = f2b(colsumg[(b * 16 + h) * 64 + d] * (1.f / 2048.f));
  }
}

// ---------------- flash attention v2 ----------------
// QBLK=128 (4 waves x 32 q-rows), KVBLK=64, double-buffered K/V, async prefetch,
// defer-max softmax, paired q-tiles (qt, 15-qt), XCD-affine bh mapping.
__global__ __launch_bounds__(256) void attn_kernel(
    const u16* __restrict__ q, const u16* __restrict__ k,
    const u16* __restrict__ vT, const int* __restrict__ pad,
    u16* __restrict__ ao)
{
  __shared__ __align__(16) u16 Ks[2][64 * 64];
  __shared__ __align__(16) u16 Vs[2][64 * 64];
  __shared__ __align__(16) float biasS[2048];

  const int tid = threadIdx.x;
  const int wid = tid >> 6, lane = tid & 63;
  const int g = lane >> 4, c = lane & 15;
  const int bid = blockIdx.x;
  const int bh = (bid & 7) | ((bid >> 6) << 3);
  const int pairi = (bid >> 3) & 7;
  const int b = bh >> 4, h = bh & 15;

  for (int i = tid; i < S; i += 256)
    biasS[i] = pad[b * S + i] ? -1e9f : 0.f;

  for (int pass = 0; pass < 2; ++pass) {
    const int qt = pass == 0 ? pairi : 15 - pairi;
    const int nt = 2 * qt + 2;
    const int qbase = qt * 128 + wid * 32;

    bfrag qf[2][2];
#pragma unroll
    for (int u = 0; u < 2; ++u)
#pragma unroll
      for (int ks = 0; ks < 2; ++ks)
        qf[u][ks] = *(const bfrag*)&q[((size_t)bh * S + qbase + u * 16 + c) * 64 + ks * 32 + g * 8];

    float m[2] = {-3.0e38f, -3.0e38f};
    float lsum[2] = {0.f, 0.f};
    f32x4 acc[2][4] = {};

    u16x8 vr[2];
#pragma unroll
    for (int p = 0; p < 2; ++p) {
      int off = (wid * 2 + p) * 1024 + (lane << 4);
      int row = off >> 7, colb = off & 127;
      gload_lds16(&k[((size_t)bh * S + row) * 64 + ((colb ^ ((row & 7) << 4)) >> 1)],
                  (char*)Ks[0] + (wid * 2 + p) * 1024);
    }
#pragma unroll
    for (int p = 0; p < 2; ++p) {
      int e = p * 256 + tid;
      int dv = e >> 3, key0 = (e & 7) << 3;
      vr[p] = *(const u16x8*)&vT[((size_t)bh * 64 + dv) * S + key0];
    }
#pragma unroll
    for (int p = 0; p < 2; ++p) {
      int e = p * 256 + tid;
      int dv = e >> 3, key0 = (e & 7) << 3;
      int ks_ = key0 >> 5, nf_ = (key0 >> 4) & 1, g0 = (key0 >> 2) & 3;
      int s0 = ks_ * 32 + g0 * 8 + nf_ * 4;
      int s1 = ks_ * 32 + (g0 + 1) * 8 + nf_ * 4;
      int x = (dv & 7) << 3;
      u16x4 lo = {vr[p][0], vr[p][1], vr[p][2], vr[p][3]};
      u16x4 hi = {vr[p][4], vr[p][5], vr[p][6], vr[p][7]};
      *(u16x4*)&Vs[0][dv * 64 + (s0 ^ x)] = lo;
      *(u16x4*)&Vs[0][dv * 64 + (s1 ^ x)] = hi;
    }
    __syncthreads();

    int cur = 0;
    for (int t = 0; t < nt; ++t) {
      const bool pre = (t + 1 < nt);
      if (pre) {
#pragma unroll
        for (int p = 0; p < 2; ++p) {
          int off = (wid * 2 + p) * 1024 + (lane << 4);
          int row = off >> 7, colb = off & 127;
          gload_lds16(&k[((size_t)bh * S + (t + 1) * 64 + row) * 64 + ((colb ^ ((row & 7) << 4)) >> 1)],
                      (char*)Ks[cur ^ 1] + (wid * 2 + p) * 1024);
        }
#pragma unroll
        for (int p = 0; p < 2; ++p) {
          int e = p * 256 + tid;
          int dv = e >> 3, key0 = (e & 7) << 3;
          vr[p] = *(const u16x8*)&vT[((size_t)bh * 64 + dv) * S + (t + 1) * 64 + key0];
        }
      }

      bfrag kfr[2][4];
#pragma unroll
      for (int ks = 0; ks < 2; ++ks)
#pragma unroll
        for (int nf = 0; nf < 4; ++nf) {
          int row = nf * 16 + c;
          kfr[ks][nf] = *(const bfrag*)&Ks[cur][row * 64 + ((ks * 32 + g * 8) ^ ((row & 7) << 3))];
        }
      f32x4 sc[2][4] = {};
#pragma unroll
      for (int u = 0; u < 2; ++u)
#pragma unroll
        for (int ks = 0; ks < 2; ++ks)
#pragma unroll
          for (int nf = 0; nf < 4; ++nf)
            sc[u][nf] = mfma16(kfr[ks][nf], qf[u][ks], sc[u][nf]);

      float4 kb[4];
#pragma unroll
      for (int nf = 0; nf < 4; ++nf)
        kb[nf] = *(const float4*)&biasS[t * 64 + nf * 16 + g * 4];

      bfrag pa[2][2];
#pragma unroll
      for (int u = 0; u < 2; ++u) {
        float sval[4][4];
#pragma unroll
        for (int nf = 0; nf < 4; ++nf) {
          sval[nf][0] = fmaf(sc[u][nf][0], 0.125f, kb[nf].x);
          sval[nf][1] = fmaf(sc[u][nf][1], 0.125f, kb[nf].y);
          sval[nf][2] = fmaf(sc[u][nf][2], 0.125f, kb[nf].z);
          sval[nf][3] = fmaf(sc[u][nf][3], 0.125f, kb[nf].w);
        }
        if (t * 64 + 63 > qbase + u * 16) {
          int qrow_g = qbase + u * 16 + c;
#pragma unroll
          for (int nf = 0; nf < 4; ++nf)
#pragma unroll
            for (int r = 0; r < 4; ++r)
              if (t * 64 + nf * 16 + g * 4 + r > qrow_g) sval[nf][r] = -1e9f;
        }
        float pm = sval[0][0];
#pragma unroll
        for (int nf = 0; nf < 4; ++nf)
#pragma unroll
          for (int r = 0; r < 4; ++r) pm = fmaxf(pm, sval[nf][r]);
        pm = fmaxf(pm, __shfl_xor(pm, 16));
        pm = fmaxf(pm, __shfl_xor(pm, 32));
        if (!__all(pm - m[u] <= 8.f)) {
          float mn = fmaxf(m[u], pm);
          float fac = __expf(m[u] - mn);
          lsum[u] *= fac;
#pragma unroll
          for (int nf = 0; nf < 4; ++nf)
#pragma unroll
            for (int j = 0; j < 4; ++j) acc[u][nf][j] *= fac;
          m[u] = mn;
        }
        float p16v[4][4];
        float rs = 0.f;
#pragma unroll
        for (int nf = 0; nf < 4; ++nf)
#pragma unroll
          for (int r = 0; r < 4; ++r) {
            float pv = __expf(sval[nf][r] - m[u]);
            p16v[nf][r] = pv;
            rs += pv;
          }
        rs += __shfl_xor(rs, 16);
        rs += __shfl_xor(rs, 32);
        lsum[u] += rs;
#pragma unroll
        for (int ks = 0; ks < 2; ++ks) {
          union { u32 w[4]; bfrag f; } pu;
#pragma unroll
          for (int tt = 0; tt < 4; ++tt)
            pu.w[tt] = cvtpk(p16v[2 * ks + (tt >> 1)][2 * (tt & 1)],
                             p16v[2 * ks + (tt >> 1)][2 * (tt & 1) + 1]);
          pa[u][ks] = pu.f;
        }
      }

      bfrag vfr[2][4];
#pragma unroll
      for (int ks = 0; ks < 2; ++ks)
#pragma unroll
        for (int nf = 0; nf < 4; ++nf) {
          int row = nf * 16 + c;
          vfr[ks][nf] = *(const bfrag*)&Vs[cur][row * 64 + ((ks * 32 + g * 8) ^ ((row & 7) << 3))];
        }
#pragma unroll
      for (int u = 0; u < 2; ++u)
#pragma unroll
        for (int ks = 0; ks < 2; ++ks)
#pragma unroll
          for (int nf = 0; nf < 4; ++nf)
            acc[u][nf] = mfma16(vfr[ks][nf], pa[u][ks], acc[u][nf]);

      if (pre) {
#pragma unroll
        for (int p = 0; p < 2; ++p) {
          int e = p * 256 + tid;
          int dv = e >> 3, key0 = (e & 7) << 3;
          int ks_ = key0 >> 5, nf_ = (key0 >> 4) & 1, g0 = (key0 >> 2) & 3;
          int s0 = ks_ * 32 + g0 * 8 + nf_ * 4;
          int s1 = ks_ * 32 + (g0 + 1) * 8 + nf_ * 4;
          int x = (dv & 7) << 3;
          u16x4 lo = {vr[p][0], vr[p][1], vr[p][2], vr[p][3]};
          u16x4 hi = {vr[p][4], vr[p][5], vr[p][6], vr[p][7]};
          *(u16x4*)&Vs[cur ^ 1][dv * 64 + (s0 ^ x)] = lo;
          *(u16x4*)&Vs[cur ^ 1][dv * 64 + (s1 ^ x)] = hi;
        }
      }
      __syncthreads();
      cur ^= 1;
    }

#pragma unroll
    for (int u = 0; u < 2; ++u) {
      const float inv = 1.f / lsum[u];
      const int qrow = qbase + u * 16 + c;
#pragma unroll
      for (int nf = 0; nf < 4; ++nf) {
        u16x4 ov;
#pragma unroll
        for (int j = 0; j < 4; ++j) ov[j] = f2b(acc[u][nf][j] * inv);
        *(u16x4*)&ao[((size_t)b * S + qrow) * 1024 + h * 64 + nf * 16 + g * 4] = ov;
      }
    }
  }
}

// ---------------- launch ----------------
extern "C" void kernel_launch(void* const* d_in, const int* in_sizes, int n_in,
                              void* d_out, int out_size, void* d_ws, size_t ws_size,
                              hipStream_t stream)
{
  const float* Q  = (const float*)d_in[0];
  const float* Kk = (const float*)d_in[1];
  const float* V  = (const float*)d_in[2];
  const int* pad  = (const int*)d_in[3];
  const float* Wq = (const float*)d_in[4];
  const float* bq = (const float*)d_in[5];
  const float* Wk = (const float*)d_in[6];
  const float* bk = (const float*)d_in[7];
  const float* Wv = (const float*)d_in[8];
  const float* bv = (const float*)d_in[9];
  const float* Wo = (const float*)d_in[10];
  const float* bo = (const float*)d_in[11];

  // ws layout (u16 elems):
  // [0,4M): 4x WT | [4M,8M): q | [8M,12M): k | [12M,16M): v/ao | [16M,20M): vT
  // [20M,32M): bf16 copies of Q,K,V (big path only)  => 64 MiB
  u16* ws  = (u16*)d_ws;
  u16* WoT = ws + 3 * (size_t)(1u << 20);
  u16* qb  = ws + 4 * (size_t)(1u << 20);
  u16* kb  = ws + 8 * (size_t)(1u << 20);
  u16* vb  = ws + 12 * (size_t)(1u << 20);
  u16* vTb = ws + 16 * (size_t)(1u << 20);
  u16* Abf = ws + 20 * (size_t)(1u << 20);
  u16* ao  = vb;
  float* colsumg = (float*)(ws + (1u << 20));  // WkT region dead after qkv

  const bool big = ws_size >= (size_t)64 * 1024 * 1024;

  wtrans_kernel<<<dim3(16, 16, 4), 256, 0, stream>>>(Wq, Wk, Wv, Wo, ws);
  if (big) {
    cvt_kernel<<<dim3(2048, 3), 256, 0, stream>>>(Q, Kk, V, Abf);
    qkv_gemm_b16<<<768, 256, 0, stream>>>(Abf, ws, bq, bk, bv, ws);
  } else {
    qkv_gemm_f32<<<dim3(8, 32, 3), 256, 0, stream>>>(Q, Kk, V, ws, bq, bk, bv, ws);
  }
  hipMemsetAsync(colsumg, 0, 32 * 64 * sizeof(float), stream);
  vtrans_kernel<<<dim3(32, 32), 256, 0, stream>>>(vb, vTb, colsumg);
  attn_kernel<<<256, 256, 0, stream>>>(qb, kb, vTb, pad, ao);
  fixup_kernel<<<2, 256, 0, stream>>>(pad, colsumg, ao);
  out_gemm<<<256, 256, 0, stream>>>(ao, WoT, bo, d_out);
}

// Round 7
// 138.877 us; speedup vs baseline: 2.4613x; 1.1101x over previous
//
#include <hip/hip_runtime.h>

typedef unsigned short u16;
typedef unsigned int u32;

typedef __attribute__((ext_vector_type(8))) short bfrag;   // 8 bf16 for MFMA A/B
typedef __attribute__((ext_vector_type(4))) float f32x4;
typedef __attribute__((ext_vector_type(8))) u16 u16x8;
typedef __attribute__((ext_vector_type(4))) u16 u16x4;

constexpr int S = 2048;
constexpr int HN = 16;

__device__ __forceinline__ u16 f2b(float f) {
  u32 u = __builtin_bit_cast(u32, f);
  return (u16)((u + 0x7FFFu + ((u >> 16) & 1u)) >> 16);  // RNE f32->bf16
}
__device__ __forceinline__ float b2f(u16 v) {
  u32 u = (u32)v << 16;
  return __builtin_bit_cast(float, u);
}
__device__ __forceinline__ u32 cvtpk(float lo, float hi) {
  u32 d;
  asm("v_cvt_pk_bf16_f32 %0, %1, %2" : "=v"(d) : "v"(lo), "v"(hi));
  return d;
}

__device__ __forceinline__ f32x4 mfma16(bfrag a, bfrag b, f32x4 c) {
  return __builtin_amdgcn_mfma_f32_16x16x32_bf16(a, b, c, 0, 0, 0);
}

__device__ __forceinline__ void gload_lds16(const void* g, void* l) {
  __builtin_amdgcn_global_load_lds(
      (const __attribute__((address_space(1))) u32*)g,
      (__attribute__((address_space(3))) u32*)l, 16, 0, 0);
}

// ---------------- W transpose + f32->bf16:  WT[n][k] = (bf16) W[k][n] ----------------
__global__ __launch_bounds__(256) void wtrans_kernel(
    const float* __restrict__ W0, const float* __restrict__ W1,
    const float* __restrict__ W2, const float* __restrict__ W3,
    u16* __restrict__ ws)
{
  const float* W = blockIdx.z == 0 ? W0 : blockIdx.z == 1 ? W1 : blockIdx.z == 2 ? W2 : W3;
  u16* WT = ws + (size_t)blockIdx.z * (1u << 20);
  __shared__ u16 tile[64 * 65];
  const int t = threadIdx.x;
  const int k0 = blockIdx.y * 64, n0 = blockIdx.x * 64;
#pragma unroll
  for (int i = 0; i < 4; ++i) {
    int idx = i * 256 + t;
    int r = idx >> 4, c4 = (idx & 15) * 4;
    float4 v = *(const float4*)&W[(size_t)(k0 + r) * 1024 + n0 + c4];
    tile[r * 65 + c4 + 0] = f2b(v.x);
    tile[r * 65 + c4 + 1] = f2b(v.y);
    tile[r * 65 + c4 + 2] = f2b(v.z);
    tile[r * 65 + c4 + 3] = f2b(v.w);
  }
  __syncthreads();
#pragma unroll
  for (int i = 0; i < 2; ++i) {
    int idx = i * 256 + t;
    int n = idx >> 3, k8 = (idx & 7) * 8;
    u16x8 o;
#pragma unroll
    for (int j = 0; j < 8; ++j) o[j] = tile[(k8 + j) * 65 + n];
    *(u16x8*)&WT[(size_t)(n0 + n) * 1024 + k0 + k8] = o;
  }
}

// ---------------- f32 -> bf16 bulk convert (Q, K, V inputs) ----------------
__global__ __launch_bounds__(256) void cvt_kernel(
    const float* __restrict__ A0, const float* __restrict__ A1,
    const float* __restrict__ A2, u16* __restrict__ outbase)
{
  const float* A = blockIdx.y == 0 ? A0 : blockIdx.y == 1 ? A1 : A2;
  u16* dst = outbase + (size_t)blockIdx.y * (4u << 20);
  size_t i = ((size_t)blockIdx.x * 256 + threadIdx.x) * 8;
  float4 v0 = *(const float4*)&A[i];
  float4 v1 = *(const float4*)&A[i + 4];
  union { u32 w[4]; u16x8 v; } o;
  o.w[0] = cvtpk(v0.x, v0.y); o.w[1] = cvtpk(v0.z, v0.w);
  o.w[2] = cvtpk(v1.x, v1.y); o.w[3] = cvtpk(v1.z, v1.w);
  *(u16x8*)&dst[i] = o.v;
}

// ------- v [B,H,S,64] -> vT [B,H,64,S] PERMUTED+SWIZZLED, fused column-sum -------
// Output layout per 64-key tile: col = slot(key) ^ ((dv&7)<<3), where
// key = 32a+16b+8cc+4d+e  ->  slot = 32a+16cc+8d+4b+e  (matches P-register order).
__global__ __launch_bounds__(256) void vtrans_kernel(
    const u16* __restrict__ v, u16* __restrict__ vT, float* __restrict__ colsumg)
{
  __shared__ u16 tile[64 * 65];
  const int t = threadIdx.x;
  const int s0 = blockIdx.x * 64;
  const int bh = blockIdx.y;
#pragma unroll
  for (int i = 0; i < 2; ++i) {
    int idx = i * 256 + t;
    int r = idx >> 3, c8 = (idx & 7) * 8;
    u16x8 in = *(const u16x8*)&v[((size_t)bh * S + s0 + r) * 64 + c8];
#pragma unroll
    for (int j = 0; j < 8; ++j) tile[r * 65 + c8 + j] = in[j];
  }
  __syncthreads();
#pragma unroll
  for (int i = 0; i < 2; ++i) {
    int idx = i * 256 + t;
    int dv = idx >> 3, s8 = (idx & 7) * 8;   // keys s8..s8+7 of this tile
    u16x8 o;
    float psum = 0.f;
#pragma unroll
    for (int j = 0; j < 8; ++j) {
      o[j] = tile[(s8 + j) * 65 + dv];
      psum += b2f(o[j]);
    }
    int a = s8 >> 5, bb = (s8 >> 4) & 1, cc = (s8 >> 3) & 1;
    int s0l = a * 32 + cc * 16 + bb * 4;     // keys s8..s8+3 -> slots s0l..s0l+3
    int x = (dv & 7) << 3;
    u16x4 lo = {o[0], o[1], o[2], o[3]};
    u16x4 hi = {o[4], o[5], o[6], o[7]};
    size_t rowbase = ((size_t)bh * 64 + dv) * S + s0;
    *(u16x4*)&vT[rowbase + (s0l ^ x)] = lo;
    *(u16x4*)&vT[rowbase + ((s0l + 8) ^ x)] = hi;
    psum += __shfl_xor(psum, 1);
    psum += __shfl_xor(psum, 2);
    psum += __shfl_xor(psum, 4);
    if ((t & 7) == 0) atomicAdd(&colsumg[bh * 64 + dv], psum);
  }
}

// ---------------- shared GEMM core: C[M,N] = A[M,K] * Bt[N,K]^T + bias ----------------
// AMODE 0: A f32 reg-staged (convert to bf16); 2: A bf16 via global_load_lds.
// CMODE 0: scatter-store bf16 to [B,H,S,64] (kswz: bake XOR swizzle); 1: f32 linear.
template <int AMODE, int CMODE>
__device__ __forceinline__ void gemm_core(
    u16* As, u16* Bs,
    const void* __restrict__ Av, const u16* __restrict__ Bt,
    const float* __restrict__ bias, void* __restrict__ Cout,
    int N, int K, int bn, int bm, int kswz)
{
  const int tid = threadIdx.x;
  const int wid = tid >> 6, lane = tid & 63;
  const int g = lane >> 4, c = lane & 15;
  const int wr = wid >> 1, wc = wid & 1;

  f32x4 acc[4][4] = {};

  const int nkt = K >> 6;
  for (int kt = 0; kt < nkt; ++kt) {
    if (AMODE == 0) {
      const float* A = (const float*)Av;
#pragma unroll
      for (int p = 0; p < 4; ++p) {
        int e = (p * 256 + tid) * 8;
        int row = e >> 6, col = e & 63;
        const float* src = &A[(size_t)(bm * 128 + row) * K + kt * 64 + col];
        float4 v0 = *(const float4*)src;
        float4 v1 = *(const float4*)(src + 4);
        u16x8 w;
        w[0] = f2b(v0.x); w[1] = f2b(v0.y); w[2] = f2b(v0.z); w[3] = f2b(v0.w);
        w[4] = f2b(v1.x); w[5] = f2b(v1.y); w[6] = f2b(v1.z); w[7] = f2b(v1.w);
        *(u16x8*)&As[row * 64 + (col ^ ((row & 7) << 3))] = w;
      }
    } else {
      const u16* A = (const u16*)Av;
#pragma unroll
      for (int p = 0; p < 4; ++p) {
        int off = (p * 4 + wid) * 1024 + (lane << 4);
        int row = off >> 7, colb = off & 127;
        gload_lds16(&A[(size_t)(bm * 128 + row) * K + kt * 64 +
                       ((colb ^ ((row & 7) << 4)) >> 1)],
                    (char*)As + (p * 4 + wid) * 1024);
      }
    }
#pragma unroll
    for (int p = 0; p < 4; ++p) {
      int off = (p * 4 + wid) * 1024 + (lane << 4);
      int row = off >> 7, colb = off & 127;
      gload_lds16(&Bt[(size_t)(bn * 128 + row) * K + kt * 64 +
                      ((colb ^ ((row & 7) << 4)) >> 1)],
                  (char*)Bs + (p * 4 + wid) * 1024);
    }
    __syncthreads();

#pragma unroll
    for (int ks = 0; ks < 2; ++ks) {
      bfrag af[4], bf[4];
#pragma unroll
      for (int mi = 0; mi < 4; ++mi) {
        int row = wr * 64 + mi * 16 + c;
        af[mi] = *(const bfrag*)&As[row * 64 + ((ks * 32 + g * 8) ^ ((row & 7) << 3))];
      }
#pragma unroll
      for (int ni = 0; ni < 4; ++ni) {
        int row = wc * 64 + ni * 16 + c;
        bf[ni] = *(const bfrag*)&Bs[row * 64 + ((ks * 32 + g * 8) ^ ((row & 7) << 3))];
      }
#pragma unroll
      for (int mi = 0; mi < 4; ++mi)
#pragma unroll
        for (int ni = 0; ni < 4; ++ni)
          acc[mi][ni] = mfma16(af[mi], bf[ni], acc[mi][ni]);
    }
    __syncthreads();
  }

#pragma unroll
  for (int mi = 0; mi < 4; ++mi) {
#pragma unroll
    for (int ni = 0; ni < 4; ++ni) {
#pragma unroll
      for (int j = 0; j < 4; ++j) {
        int rowg = bm * 128 + wr * 64 + mi * 16 + g * 4 + j;
        int colg = bn * 128 + wc * 64 + ni * 16 + c;
        float val = acc[mi][ni][j] + bias[colg];
        if (CMODE == 0) {
          int b = rowg >> 11, s = rowg & (S - 1);
          int h = colg >> 6, d = colg & 63;
          if (kswz) d ^= (s & 7) << 3;   // bake attn K-staging swizzle
          ((u16*)Cout)[((size_t)((b * HN + h) * S + s)) * 64 + d] = f2b(val);
        } else {
          ((float*)Cout)[(size_t)rowg * N + colg] = val;
        }
      }
    }
  }
}

// pure-bf16 QKV projection, 1D grid 768, XCD-chunked decode
__global__ __launch_bounds__(256) void qkv_gemm_b16(
    const u16* __restrict__ Abase, const u16* __restrict__ WTbase,
    const float* __restrict__ b0, const float* __restrict__ b1, const float* __restrict__ b2,
    u16* __restrict__ wsbase)
{
  __shared__ __align__(16) u16 As[128 * 64];
  __shared__ __align__(16) u16 Bs[128 * 64];
  const int bid = blockIdx.x;
  const int l = (bid & 7) * 96 + (bid >> 3);
  const int z = l >> 8, rem = l & 255, bm = rem >> 3, bn = rem & 7;
  const u16* A = Abase + (size_t)z * (4u << 20);
  const u16* Bt = WTbase + (size_t)z * (1u << 20);
  const float* bias = z == 0 ? b0 : z == 1 ? b1 : b2;
  u16* C = wsbase + (size_t)(4 + 4 * z) * (1u << 20);
  gemm_core<2, 0>(As, Bs, A, Bt, bias, C, 1024, 1024, bn, bm, z == 1);
}

// fallback (small ws): f32-A projection, z-grid
__global__ __launch_bounds__(256) void qkv_gemm_f32(
    const float* __restrict__ A0, const float* __restrict__ A1, const float* __restrict__ A2,
    const u16* __restrict__ WTbase,
    const float* __restrict__ b0, const float* __restrict__ b1, const float* __restrict__ b2,
    u16* __restrict__ wsbase)
{
  __shared__ __align__(16) u16 As[128 * 64];
  __shared__ __align__(16) u16 Bs[128 * 64];
  const int z = blockIdx.z;
  const float* A = z == 0 ? A0 : z == 1 ? A1 : A2;
  const u16* Bt = WTbase + (size_t)z * (1u << 20);
  const float* bias = z == 0 ? b0 : z == 1 ? b1 : b2;
  u16* C = wsbase + (size_t)(4 + 4 * z) * (1u << 20);
  gemm_core<0, 0>(As, Bs, A, Bt, bias, C, 1024, 1024, blockIdx.x, blockIdx.y, z == 1);
}

__global__ __launch_bounds__(256) void out_gemm(
    const u16* __restrict__ Av, const u16* __restrict__ Bt,
    const float* __restrict__ bias, void* __restrict__ Cout)
{
  __shared__ __align__(16) u16 As[128 * 64];
  __shared__ __align__(16) u16 Bs[128 * 64];
  const int bid = blockIdx.x;
  const int l = (bid & 7) * 32 + (bid >> 3);
  const int bm = l >> 3, bn = l & 7;
  gemm_core<2, 1>(As, Bs, Av, Bt, bias, Cout, 1024, 1024, bn, bm, 0);
}

// ---------------- flash attention v3 ----------------
// 512 blocks (2/CU), QBLK=64 (4 waves x 16 rows), paired q-tiles (qt, 31-qt) => 33
// KV-tiles/block uniform. K and V both staged via global_load_lds (swizzle baked in
// global layouts). Double-buffered, defer-max softmax, setprio MFMA, fused fixup.
__global__ __launch_bounds__(256) void attn_kernel(
    const u16* __restrict__ q, const u16* __restrict__ k,
    const u16* __restrict__ vT, const int* __restrict__ pad,
    const float* __restrict__ colsumg, u16* __restrict__ ao)
{
  __shared__ __align__(16) u16 Ks[2][64 * 64];
  __shared__ __align__(16) u16 Vs[2][64 * 64];
  __shared__ __align__(16) float biasS[2048];
  __shared__ int fzs;

  const int tid = threadIdx.x;
  const int wid = tid >> 6, lane = tid & 63;
  const int g = lane >> 4, c = lane & 15;
  const int bid = blockIdx.x;
  const int bh = (bid & 7) * 4 + ((bid >> 3) & 3);  // 4 bh per XCD slot
  const int pairi = bid >> 5;                        // [0,16)
  const int b = bh >> 4, h = bh & 15;

  if (tid == 0) fzs = S;
  __syncthreads();
  int localmin = S;
  for (int i = tid; i < S; i += 256) {
    int pv = pad[b * S + i];
    biasS[i] = pv ? -1e9f : 0.f;
    if (pv == 0) localmin = min(localmin, i);
  }
  atomicMin(&fzs, localmin);

  const size_t kbase = (size_t)bh * S * 64;
  const size_t vbase = (size_t)bh * 64 * S;
  const int sb = (wid * 2) * 1024 + (lane << 4);     // this wave's staging byte offsets
  const int sb2 = sb + 1024;

  for (int pass = 0; pass < 2; ++pass) {
    const int qt = pass == 0 ? pairi : 31 - pairi;
    const int nt = qt + 1;
    const int qrow = qt * 64 + wid * 16 + c;

    bfrag qf[2];
#pragma unroll
    for (int ks = 0; ks < 2; ++ks)
      qf[ks] = *(const bfrag*)&q[((size_t)bh * S + qrow) * 64 + ks * 32 + g * 8];

    float m = -3.0e38f, lsum = 0.f;
    f32x4 acc[4] = {};

#define STAGE(buf, t)                                                              \
    gload_lds16(&k[kbase + (size_t)(t) * 4096 + (sb >> 1)],                        \
                (char*)Ks[buf] + wid * 2048);                                      \
    gload_lds16(&k[kbase + (size_t)(t) * 4096 + (sb2 >> 1)],                       \
                (char*)Ks[buf] + wid * 2048 + 1024);                               \
    gload_lds16(&vT[vbase + (size_t)(sb >> 7) * S + (t) * 64 + ((sb & 127) >> 1)], \
                (char*)Vs[buf] + wid * 2048);                                      \
    gload_lds16(&vT[vbase + (size_t)(sb2 >> 7) * S + (t) * 64 + ((sb2 & 127) >> 1)],\
                (char*)Vs[buf] + wid * 2048 + 1024);

    STAGE(0, 0);
    __syncthreads();

    int cur = 0;
    for (int t = 0; t < nt; ++t) {
      if (t + 1 < nt) { STAGE(cur ^ 1, t + 1); }

      // QK^T (swapped): lane owns q-row c; D[key][qrow]
      f32x4 sc[4] = {};
      __builtin_amdgcn_s_setprio(1);
#pragma unroll
      for (int ks = 0; ks < 2; ++ks)
#pragma unroll
        for (int nf = 0; nf < 4; ++nf) {
          int row = nf * 16 + c;
          bfrag kf = *(const bfrag*)&Ks[cur][row * 64 + ((ks * 32 + g * 8) ^ ((row & 7) << 3))];
          sc[nf] = mfma16(kf, qf[ks], sc[nf]);
        }
      __builtin_amdgcn_s_setprio(0);

      float sval[4][4];
#pragma unroll
      for (int nf = 0; nf < 4; ++nf) {
        float4 kb4 = *(const float4*)&biasS[t * 64 + nf * 16 + g * 4];
        sval[nf][0] = fmaf(sc[nf][0], 0.125f, kb4.x);
        sval[nf][1] = fmaf(sc[nf][1], 0.125f, kb4.y);
        sval[nf][2] = fmaf(sc[nf][2], 0.125f, kb4.z);
        sval[nf][3] = fmaf(sc[nf][3], 0.125f, kb4.w);
      }
      if (t == qt) {           // only the diagonal tile needs causal masking
#pragma unroll
        for (int nf = 0; nf < 4; ++nf)
#pragma unroll
          for (int r = 0; r < 4; ++r)
            if (nf * 16 + g * 4 + r > wid * 16 + c) sval[nf][r] = -1e9f;
      }

      float pm = sval[0][0];
#pragma unroll
      for (int nf = 0; nf < 4; ++nf)
#pragma unroll
        for (int r = 0; r < 4; ++r) pm = fmaxf(pm, sval[nf][r]);
      pm = fmaxf(pm, __shfl_xor(pm, 16));
      pm = fmaxf(pm, __shfl_xor(pm, 32));
      if (!__all(pm - m <= 8.f)) {       // defer-max
        float mn = fmaxf(m, pm);
        float fac = __expf(m - mn);
        lsum *= fac;
#pragma unroll
        for (int nf = 0; nf < 4; ++nf)
#pragma unroll
          for (int j = 0; j < 4; ++j) acc[nf][j] *= fac;
        m = mn;
      }
      float p16v[4][4];
      float rs = 0.f;
#pragma unroll
      for (int nf = 0; nf < 4; ++nf)
#pragma unroll
        for (int r = 0; r < 4; ++r) {
          float pv = __expf(sval[nf][r] - m);
          p16v[nf][r] = pv;
          rs += pv;
        }
      rs += __shfl_xor(rs, 16);
      rs += __shfl_xor(rs, 32);
      lsum += rs;

      bfrag pa[2];
#pragma unroll
      for (int ks = 0; ks < 2; ++ks) {
        union { u32 w[4]; bfrag f; } pu;
#pragma unroll
        for (int tt = 0; tt < 4; ++tt)
          pu.w[tt] = cvtpk(p16v[2 * ks + (tt >> 1)][2 * (tt & 1)],
                           p16v[2 * ks + (tt >> 1)][2 * (tt & 1) + 1]);
        pa[ks] = pu.f;
      }

      // PV (swapped): D[dv][qrow]
      __builtin_amdgcn_s_setprio(1);
#pragma unroll
      for (int ks = 0; ks < 2; ++ks)
#pragma unroll
        for (int nf = 0; nf < 4; ++nf) {
          int row = nf * 16 + c;
          bfrag vf = *(const bfrag*)&Vs[cur][row * 64 + ((ks * 32 + g * 8) ^ ((row & 7) << 3))];
          acc[nf] = mfma16(vf, pa[ks], acc[nf]);
        }
      __builtin_amdgcn_s_setprio(0);

      __syncthreads();
      cur ^= 1;
    }
#undef STAGE

    // epilogue (+ fused fully-masked-row fixup: uniform over all 2048 keys)
    const int fz = fzs;
    const float inv = 1.f / lsum;
#pragma unroll
    for (int nf = 0; nf < 4; ++nf) {
      u16x4 ov;
      if (qrow < fz) {
#pragma unroll
        for (int j = 0; j < 4; ++j)
          ov[j] = f2b(colsumg[bh * 64 + nf * 16 + g * 4 + j] * (1.f / 2048.f));
      } else {
#pragma unroll
        for (int j = 0; j < 4; ++j) ov[j] = f2b(acc[nf][j] * inv);
      }
      *(u16x4*)&ao[((size_t)b * S + qrow) * 1024 + h * 64 + nf * 16 + g * 4] = ov;
    }
  }
}

// ---------------- launch ----------------
extern "C" void kernel_launch(void* const* d_in, const int* in_sizes, int n_in,
                              void* d_out, int out_size, void* d_ws, size_t ws_size,
                              hipStream_t stream)
{
  const float* Q  = (const float*)d_in[0];
  const float* Kk = (const float*)d_in[1];
  const float* V  = (const float*)d_in[2];
  const int* pad  = (const int*)d_in[3];
  const float* Wq = (const float*)d_in[4];
  const float* bq = (const float*)d_in[5];
  const float* Wk = (const float*)d_in[6];
  const float* bk = (const float*)d_in[7];
  const float* Wv = (const float*)d_in[8];
  const float* bv = (const float*)d_in[9];
  const float* Wo = (const float*)d_in[10];
  const float* bo = (const float*)d_in[11];

  u16* ws  = (u16*)d_ws;
  u16* WoT = ws + 3 * (size_t)(1u << 20);
  u16* qb  = ws + 4 * (size_t)(1u << 20);
  u16* kb  = ws + 8 * (size_t)(1u << 20);
  u16* vb  = ws + 12 * (size_t)(1u << 20);
  u16* vTb = ws + 16 * (size_t)(1u << 20);
  u16* Abf = ws + 20 * (size_t)(1u << 20);
  u16* ao  = vb;
  float* colsumg = (float*)(ws + (1u << 20));  // WkT region dead after qkv

  const bool big = ws_size >= (size_t)64 * 1024 * 1024;

  wtrans_kernel<<<dim3(16, 16, 4), 256, 0, stream>>>(Wq, Wk, Wv, Wo, ws);
  if (big) {
    cvt_kernel<<<dim3(2048, 3), 256, 0, stream>>>(Q, Kk, V, Abf);
    qkv_gemm_b16<<<768, 256, 0, stream>>>(Abf, ws, bq, bk, bv, ws);
  } else {
    qkv_gemm_f32<<<dim3(8, 32, 3), 256, 0, stream>>>(Q, Kk, V, ws, bq, bk, bv, ws);
  }
  hipMemsetAsync(colsumg, 0, 32 * 64 * sizeof(float), stream);
  vtrans_kernel<<<dim3(32, 32), 256, 0, stream>>>(vb, vTb, colsumg);
  attn_kernel<<<512, 256, 0, stream>>>(qb, kb, vTb, pad, colsumg, ao);
  out_gemm<<<256, 256, 0, stream>>>(ao, WoT, bo, d_out);
}

// Round 8
// 136.341 us; speedup vs baseline: 2.5070x; 1.0186x over previous
//
#include <hip/hip_runtime.h>

typedef unsigned short u16;
typedef unsigned int u32;

typedef __attribute__((ext_vector_type(8))) short bfrag;   // 8 bf16 for MFMA A/B
typedef __attribute__((ext_vector_type(4))) float f32x4;
typedef __attribute__((ext_vector_type(8))) u16 u16x8;
typedef __attribute__((ext_vector_type(4))) u16 u16x4;

constexpr int S = 2048;
constexpr int HN = 16;
constexpr float QSCALE = 0.18033688011112042f;  // 0.125 * log2(e)
constexpr float NBIG   = -1.442695e9f;          // -1e9 * log2(e) (uniform masked constant)

__device__ __forceinline__ u16 f2b(float f) {
  u32 u = __builtin_bit_cast(u32, f);
  return (u16)((u + 0x7FFFu + ((u >> 16) & 1u)) >> 16);  // RNE f32->bf16
}
__device__ __forceinline__ float b2f(u16 v) {
  u32 u = (u32)v << 16;
  return __builtin_bit_cast(float, u);
}
__device__ __forceinline__ u32 cvtpk(float lo, float hi) {
  u32 d;
  asm("v_cvt_pk_bf16_f32 %0, %1, %2" : "=v"(d) : "v"(lo), "v"(hi));
  return d;
}
__device__ __forceinline__ float fexp2(float x) { return __builtin_amdgcn_exp2f(x); }

__device__ __forceinline__ f32x4 mfma16(bfrag a, bfrag b, f32x4 c) {
  return __builtin_amdgcn_mfma_f32_16x16x32_bf16(a, b, c, 0, 0, 0);
}

__device__ __forceinline__ void gload_lds16(const void* g, void* l) {
  __builtin_amdgcn_global_load_lds(
      (const __attribute__((address_space(1))) u32*)g,
      (__attribute__((address_space(3))) u32*)l, 16, 0, 0);
}

// ---------------- W transpose + f32->bf16 (+ exp2-domain scale for Wq) ----------------
__global__ __launch_bounds__(256) void wtrans_kernel(
    const float* __restrict__ W0, const float* __restrict__ W1,
    const float* __restrict__ W2, const float* __restrict__ W3,
    u16* __restrict__ ws)
{
  const float* W = blockIdx.z == 0 ? W0 : blockIdx.z == 1 ? W1 : blockIdx.z == 2 ? W2 : W3;
  const float sc = blockIdx.z == 0 ? QSCALE : 1.0f;
  u16* WT = ws + (size_t)blockIdx.z * (1u << 20);
  __shared__ u16 tile[64 * 65];
  const int t = threadIdx.x;
  const int k0 = blockIdx.y * 64, n0 = blockIdx.x * 64;
#pragma unroll
  for (int i = 0; i < 4; ++i) {
    int idx = i * 256 + t;
    int r = idx >> 4, c4 = (idx & 15) * 4;
    float4 v = *(const float4*)&W[(size_t)(k0 + r) * 1024 + n0 + c4];
    tile[r * 65 + c4 + 0] = f2b(v.x * sc);
    tile[r * 65 + c4 + 1] = f2b(v.y * sc);
    tile[r * 65 + c4 + 2] = f2b(v.z * sc);
    tile[r * 65 + c4 + 3] = f2b(v.w * sc);
  }
  __syncthreads();
#pragma unroll
  for (int i = 0; i < 2; ++i) {
    int idx = i * 256 + t;
    int n = idx >> 3, k8 = (idx & 7) * 8;
    u16x8 o;
#pragma unroll
    for (int j = 0; j < 8; ++j) o[j] = tile[(k8 + j) * 65 + n];
    *(u16x8*)&WT[(size_t)(n0 + n) * 1024 + k0 + k8] = o;
  }
}

// ---------------- f32 -> bf16 bulk convert (Q, K, V inputs) ----------------
__global__ __launch_bounds__(256) void cvt_kernel(
    const float* __restrict__ A0, const float* __restrict__ A1,
    const float* __restrict__ A2, u16* __restrict__ outbase)
{
  const float* A = blockIdx.y == 0 ? A0 : blockIdx.y == 1 ? A1 : A2;
  u16* dst = outbase + (size_t)blockIdx.y * (4u << 20);
  size_t i = ((size_t)blockIdx.x * 256 + threadIdx.x) * 8;
  float4 v0 = *(const float4*)&A[i];
  float4 v1 = *(const float4*)&A[i + 4];
  union { u32 w[4]; u16x8 v; } o;
  o.w[0] = cvtpk(v0.x, v0.y); o.w[1] = cvtpk(v0.z, v0.w);
  o.w[2] = cvtpk(v1.x, v1.y); o.w[3] = cvtpk(v1.z, v1.w);
  *(u16x8*)&dst[i] = o.v;
}

// ------- v [B,H,S,64] -> vT [B,H,64,S] PERMUTED+SWIZZLED, fused column-sum -------
__global__ __launch_bounds__(256) void vtrans_kernel(
    const u16* __restrict__ v, u16* __restrict__ vT, float* __restrict__ colsumg)
{
  __shared__ u16 tile[64 * 65];
  const int t = threadIdx.x;
  const int s0 = blockIdx.x * 64;
  const int bh = blockIdx.y;
#pragma unroll
  for (int i = 0; i < 2; ++i) {
    int idx = i * 256 + t;
    int r = idx >> 3, c8 = (idx & 7) * 8;
    u16x8 in = *(const u16x8*)&v[((size_t)bh * S + s0 + r) * 64 + c8];
#pragma unroll
    for (int j = 0; j < 8; ++j) tile[r * 65 + c8 + j] = in[j];
  }
  __syncthreads();
#pragma unroll
  for (int i = 0; i < 2; ++i) {
    int idx = i * 256 + t;
    int dv = idx >> 3, s8 = (idx & 7) * 8;
    u16x8 o;
    float psum = 0.f;
#pragma unroll
    for (int j = 0; j < 8; ++j) {
      o[j] = tile[(s8 + j) * 65 + dv];
      psum += b2f(o[j]);
    }
    int a = s8 >> 5, bb = (s8 >> 4) & 1, cc = (s8 >> 3) & 1;
    int s0l = a * 32 + cc * 16 + bb * 4;
    int x = (dv & 7) << 3;
    u16x4 lo = {o[0], o[1], o[2], o[3]};
    u16x4 hi = {o[4], o[5], o[6], o[7]};
    size_t rowbase = ((size_t)bh * 64 + dv) * S + s0;
    *(u16x4*)&vT[rowbase + (s0l ^ x)] = lo;
    *(u16x4*)&vT[rowbase + ((s0l + 8) ^ x)] = hi;
    psum += __shfl_xor(psum, 1);
    psum += __shfl_xor(psum, 2);
    psum += __shfl_xor(psum, 4);
    if ((t & 7) == 0) atomicAdd(&colsumg[bh * 64 + dv], psum);
  }
}

// ---------------- shared GEMM core: C[M,N] = A[M,K] * Bt[N,K]^T + bias*bscale ----------
template <int AMODE, int CMODE>
__device__ __forceinline__ void gemm_core(
    u16* As, u16* Bs,
    const void* __restrict__ Av, const u16* __restrict__ Bt,
    const float* __restrict__ bias, void* __restrict__ Cout,
    int N, int K, int bn, int bm, int kswz, float bscale)
{
  const int tid = threadIdx.x;
  const int wid = tid >> 6, lane = tid & 63;
  const int g = lane >> 4, c = lane & 15;
  const int wr = wid >> 1, wc = wid & 1;

  f32x4 acc[4][4] = {};

  const int nkt = K >> 6;
  for (int kt = 0; kt < nkt; ++kt) {
    if (AMODE == 0) {
      const float* A = (const float*)Av;
#pragma unroll
      for (int p = 0; p < 4; ++p) {
        int e = (p * 256 + tid) * 8;
        int row = e >> 6, col = e & 63;
        const float* src = &A[(size_t)(bm * 128 + row) * K + kt * 64 + col];
        float4 v0 = *(const float4*)src;
        float4 v1 = *(const float4*)(src + 4);
        u16x8 w;
        w[0] = f2b(v0.x); w[1] = f2b(v0.y); w[2] = f2b(v0.z); w[3] = f2b(v0.w);
        w[4] = f2b(v1.x); w[5] = f2b(v1.y); w[6] = f2b(v1.z); w[7] = f2b(v1.w);
        *(u16x8*)&As[row * 64 + (col ^ ((row & 7) << 3))] = w;
      }
    } else {
      const u16* A = (const u16*)Av;
#pragma unroll
      for (int p = 0; p < 4; ++p) {
        int off = (p * 4 + wid) * 1024 + (lane << 4);
        int row = off >> 7, colb = off & 127;
        gload_lds16(&A[(size_t)(bm * 128 + row) * K + kt * 64 +
                       ((colb ^ ((row & 7) << 4)) >> 1)],
                    (char*)As + (p * 4 + wid) * 1024);
      }
    }
#pragma unroll
    for (int p = 0; p < 4; ++p) {
      int off = (p * 4 + wid) * 1024 + (lane << 4);
      int row = off >> 7, colb = off & 127;
      gload_lds16(&Bt[(size_t)(bn * 128 + row) * K + kt * 64 +
                      ((colb ^ ((row & 7) << 4)) >> 1)],
                  (char*)Bs + (p * 4 + wid) * 1024);
    }
    __syncthreads();

#pragma unroll
    for (int ks = 0; ks < 2; ++ks) {
      bfrag af[4], bf[4];
#pragma unroll
      for (int mi = 0; mi < 4; ++mi) {
        int row = wr * 64 + mi * 16 + c;
        af[mi] = *(const bfrag*)&As[row * 64 + ((ks * 32 + g * 8) ^ ((row & 7) << 3))];
      }
#pragma unroll
      for (int ni = 0; ni < 4; ++ni) {
        int row = wc * 64 + ni * 16 + c;
        bf[ni] = *(const bfrag*)&Bs[row * 64 + ((ks * 32 + g * 8) ^ ((row & 7) << 3))];
      }
#pragma unroll
      for (int mi = 0; mi < 4; ++mi)
#pragma unroll
        for (int ni = 0; ni < 4; ++ni)
          acc[mi][ni] = mfma16(af[mi], bf[ni], acc[mi][ni]);
    }
    __syncthreads();
  }

#pragma unroll
  for (int mi = 0; mi < 4; ++mi) {
#pragma unroll
    for (int ni = 0; ni < 4; ++ni) {
#pragma unroll
      for (int j = 0; j < 4; ++j) {
        int rowg = bm * 128 + wr * 64 + mi * 16 + g * 4 + j;
        int colg = bn * 128 + wc * 64 + ni * 16 + c;
        float val = fmaf(bias[colg], bscale, acc[mi][ni][j]);
        if (CMODE == 0) {
          int b = rowg >> 11, s = rowg & (S - 1);
          int h = colg >> 6, d = colg & 63;
          if (kswz) d ^= (s & 7) << 3;
          ((u16*)Cout)[((size_t)((b * HN + h) * S + s)) * 64 + d] = f2b(val);
        } else {
          ((float*)Cout)[(size_t)rowg * N + colg] = val;
        }
      }
    }
  }
}

// pure-bf16 QKV projection, 1D grid 768, XCD-chunked decode
__global__ __launch_bounds__(256) void qkv_gemm_b16(
    const u16* __restrict__ Abase, const u16* __restrict__ WTbase,
    const float* __restrict__ b0, const float* __restrict__ b1, const float* __restrict__ b2,
    u16* __restrict__ wsbase)
{
  __shared__ __align__(16) u16 As[128 * 64];
  __shared__ __align__(16) u16 Bs[128 * 64];
  const int bid = blockIdx.x;
  const int l = (bid & 7) * 96 + (bid >> 3);
  const int z = l >> 8, rem = l & 255, bm = rem >> 3, bn = rem & 7;
  const u16* A = Abase + (size_t)z * (4u << 20);
  const u16* Bt = WTbase + (size_t)z * (1u << 20);
  const float* bias = z == 0 ? b0 : z == 1 ? b1 : b2;
  u16* C = wsbase + (size_t)(4 + 4 * z) * (1u << 20);
  gemm_core<2, 0>(As, Bs, A, Bt, bias, C, 1024, 1024, bn, bm, z == 1,
                  z == 0 ? QSCALE : 1.0f);
}

// fallback (small ws): f32-A projection, z-grid.  NOTE: Wq pre-scaled, so q output
// is scaled too; bias likewise.
__global__ __launch_bounds__(256) void qkv_gemm_f32(
    const float* __restrict__ A0, const float* __restrict__ A1, const float* __restrict__ A2,
    const u16* __restrict__ WTbase,
    const float* __restrict__ b0, const float* __restrict__ b1, const float* __restrict__ b2,
    u16* __restrict__ wsbase)
{
  __shared__ __align__(16) u16 As[128 * 64];
  __shared__ __align__(16) u16 Bs[128 * 64];
  const int z = blockIdx.z;
  const float* A = z == 0 ? A0 : z == 1 ? A1 : A2;
  const u16* Bt = WTbase + (size_t)z * (1u << 20);
  const float* bias = z == 0 ? b0 : z == 1 ? b1 : b2;
  u16* C = wsbase + (size_t)(4 + 4 * z) * (1u << 20);
  gemm_core<0, 0>(As, Bs, A, Bt, bias, C, 1024, 1024, blockIdx.x, blockIdx.y, z == 1,
                  z == 0 ? QSCALE : 1.0f);
}

__global__ __launch_bounds__(256) void out_gemm(
    const u16* __restrict__ Av, const u16* __restrict__ Bt,
    const float* __restrict__ bias, void* __restrict__ Cout)
{
  __shared__ __align__(16) u16 As[128 * 64];
  __shared__ __align__(16) u16 Bs[128 * 64];
  const int bid = blockIdx.x;
  const int l = (bid & 7) * 32 + (bid >> 3);
  const int bm = l >> 3, bn = l & 7;
  gemm_core<2, 1>(As, Bs, Av, Bt, bias, Cout, 1024, 1024, bn, bm, 0, 1.0f);
}

// ---------------- flash attention v4 ----------------
// 512 blocks (2/CU), QBLK=64 (4 waves x 16 rows), paired q-tiles (qt, 31-qt).
// KV chunk = 128 keys per barrier (two 64-key subtiles), double-buffered.
// exp2-domain softmax (scale baked into Wq), defer-max, setprio, fused fixup.
__global__ __launch_bounds__(256) void attn_kernel(
    const u16* __restrict__ q, const u16* __restrict__ k,
    const u16* __restrict__ vT, const int* __restrict__ pad,
    const float* __restrict__ colsumg, u16* __restrict__ ao)
{
  __shared__ __align__(16) u16 Ks[2][128 * 64];
  __shared__ __align__(16) u16 Vs[2][64 * 128];
  __shared__ __align__(16) float biasS[2048];
  __shared__ int fzs;

  const int tid = threadIdx.x;
  const int wid = tid >> 6, lane = tid & 63;
  const int g = lane >> 4, c = lane & 15;
  const int bid = blockIdx.x;
  const int bh = (bid & 7) * 4 + ((bid >> 3) & 3);  // 4 bh per XCD
  const int pairi = bid >> 5;                        // [0,16)
  const int b = bh >> 4, h = bh & 15;

  if (tid == 0) fzs = S;
  __syncthreads();
  int localmin = S;
  for (int i = tid; i < S; i += 256) {
    int pv = pad[b * S + i];
    biasS[i] = pv ? NBIG : 0.f;
    if (pv == 0) localmin = min(localmin, i);
  }
  atomicMin(&fzs, localmin);

  const size_t kbase = (size_t)bh * S * 64;
  const size_t vbase = (size_t)bh * 64 * S;

#define STAGE(buf, ci)                                                             \
  do {                                                                             \
    _Pragma("unroll")                                                              \
    for (int p = 0; p < 4; ++p) {                                                  \
      int ob = wid * 4096 + p * 1024;                                              \
      gload_lds16(&k[kbase + (size_t)(ci) * 8192 + (ob >> 1) + lane * 8],          \
                  (char*)Ks[buf] + ob);                                            \
      int ov = ob + (lane << 4);                                                   \
      gload_lds16(&vT[vbase + (size_t)(ov >> 8) * S + (ci) * 128 + ((ov & 255) >> 1)], \
                  (char*)Vs[buf] + ob);                                            \
    }                                                                              \
  } while (0)

#define SUBTILE(st)                                                                \
  do {                                                                             \
    const int t = 2 * ci + (st);                                                   \
    f32x4 sc[4] = {};                                                              \
    __builtin_amdgcn_s_setprio(1);                                                 \
    _Pragma("unroll")                                                              \
    for (int ks = 0; ks < 2; ++ks) {                                               \
      _Pragma("unroll")                                                            \
      for (int nf = 0; nf < 4; ++nf) {                                             \
        int row = (st) * 64 + nf * 16 + c;                                         \
        bfrag kf = *(const bfrag*)&Ks[cur][row * 64 +                              \
                     ((ks * 32 + g * 8) ^ ((row & 7) << 3))];                      \
        sc[nf] = mfma16(kf, qf[ks], sc[nf]);                                       \
      }                                                                            \
    }                                                                              \
    __builtin_amdgcn_s_setprio(0);                                                 \
    float sval[4][4];                                                              \
    _Pragma("unroll")                                                              \
    for (int nf = 0; nf < 4; ++nf) {                                               \
      float4 kb4 = *(const float4*)&biasS[t * 64 + nf * 16 + g * 4];               \
      sval[nf][0] = sc[nf][0] + kb4.x;                                             \
      sval[nf][1] = sc[nf][1] + kb4.y;                                             \
      sval[nf][2] = sc[nf][2] + kb4.z;                                             \
      sval[nf][3] = sc[nf][3] + kb4.w;                                             \
    }                                                                              \
    if (t == qt) {                                                                 \
      _Pragma("unroll")                                                            \
      for (int nf = 0; nf < 4; ++nf) {                                             \
        _Pragma("unroll")                                                          \
        for (int r = 0; r < 4; ++r)                                                \
          if (nf * 16 + g * 4 + r > wid * 16 + c) sval[nf][r] = NBIG;              \
      }                                                                            \
    }                                                                              \
    float pm = sval[0][0];                                                         \
    _Pragma("unroll")                                                              \
    for (int nf = 0; nf < 4; ++nf) {                                               \
      _Pragma("unroll")                                                            \
      for (int r = 0; r < 4; ++r) pm = fmaxf(pm, sval[nf][r]);                     \
    }                                                                              \
    pm = fmaxf(pm, __shfl_xor(pm, 16));                                            \
    pm = fmaxf(pm, __shfl_xor(pm, 32));                                            \
    if (!__all(pm - m <= 11.5416f)) {                                              \
      float mn = fmaxf(m, pm);                                                     \
      float fac = fexp2(m - mn);                                                   \
      lsum *= fac;                                                                 \
      _Pragma("unroll")                                                            \
      for (int nf = 0; nf < 4; ++nf) {                                             \
        _Pragma("unroll")                                                          \
        for (int j = 0; j < 4; ++j) acc[nf][j] *= fac;                             \
      }                                                                            \
      m = mn;                                                                      \
    }                                                                              \
    float p16v[4][4];                                                              \
    float rs = 0.f;                                                                \
    _Pragma("unroll")                                                              \
    for (int nf = 0; nf < 4; ++nf) {                                               \
      _Pragma("unroll")                                                            \
      for (int r = 0; r < 4; ++r) {                                                \
        float pv = fexp2(sval[nf][r] - m);                                         \
        p16v[nf][r] = pv;                                                          \
        rs += pv;                                                                  \
      }                                                                            \
    }                                                                              \
    rs += __shfl_xor(rs, 16);                                                      \
    rs += __shfl_xor(rs, 32);                                                      \
    lsum += rs;                                                                    \
    bfrag pa[2];                                                                   \
    _Pragma("unroll")                                                              \
    for (int ks = 0; ks < 2; ++ks) {                                               \
      union { u32 w[4]; bfrag f; } pu;                                             \
      _Pragma("unroll")                                                            \
      for (int tt = 0; tt < 4; ++tt)                                               \
        pu.w[tt] = cvtpk(p16v[2 * ks + (tt >> 1)][2 * (tt & 1)],                   \
                         p16v[2 * ks + (tt >> 1)][2 * (tt & 1) + 1]);              \
      pa[ks] = pu.f;                                                               \
    }                                                                              \
    __builtin_amdgcn_s_setprio(1);                                                 \
    _Pragma("unroll")                                                              \
    for (int ks = 0; ks < 2; ++ks) {                                               \
      _Pragma("unroll")                                                            \
      for (int nf = 0; nf < 4; ++nf) {                                             \
        int row = nf * 16 + c;                                                     \
        bfrag vf = *(const bfrag*)&Vs[cur][row * 128 +                             \
                     (((st) * 64 + ks * 32 + g * 8) ^ ((row & 7) << 3))];          \
        acc[nf] = mfma16(vf, pa[ks], acc[nf]);                                     \
      }                                                                            \
    }                                                                              \
    __builtin_amdgcn_s_setprio(0);                                                 \
  } while (0)

  for (int pass = 0; pass < 2; ++pass) {
    const int qt = pass == 0 ? pairi : 31 - pairi;
    const int nt = qt + 1;           // 64-key tiles
    const int nc = (qt >> 1) + 1;    // 128-key chunks
    const int qrow = qt * 64 + wid * 16 + c;

    bfrag qf[2];
#pragma unroll
    for (int ks = 0; ks < 2; ++ks)
      qf[ks] = *(const bfrag*)&q[((size_t)bh * S + qrow) * 64 + ks * 32 + g * 8];

    float m = -3.0e38f, lsum = 0.f;
    f32x4 acc[4] = {};

    STAGE(0, 0);
    __syncthreads();

    int cur = 0;
    for (int ci = 0; ci < nc; ++ci) {
      if (ci + 1 < nc) { STAGE(cur ^ 1, ci + 1); }
      SUBTILE(0);
      if (2 * ci + 1 < nt) SUBTILE(1);
      __syncthreads();
      cur ^= 1;
    }

    // epilogue (+ fused fully-masked-row fixup: uniform over all 2048 keys)
    const int fz = fzs;
    const float inv = 1.f / lsum;
#pragma unroll
    for (int nf = 0; nf < 4; ++nf) {
      u16x4 ov;
      if (qrow < fz) {
#pragma unroll
        for (int j = 0; j < 4; ++j)
          ov[j] = f2b(colsumg[bh * 64 + nf * 16 + g * 4 + j] * (1.f / 2048.f));
      } else {
#pragma unroll
        for (int j = 0; j < 4; ++j) ov[j] = f2b(acc[nf][j] * inv);
      }
      *(u16x4*)&ao[((size_t)b * S + qrow) * 1024 + h * 64 + nf * 16 + g * 4] = ov;
    }
  }
#undef SUBTILE
#undef STAGE
}

// ---------------- launch ----------------
extern "C" void kernel_launch(void* const* d_in, const int* in_sizes, int n_in,
                              void* d_out, int out_size, void* d_ws, size_t ws_size,
                              hipStream_t stream)
{
  const float* Q  = (const float*)d_in[0];
  const float* Kk = (const float*)d_in[1];
  const float* V  = (const float*)d_in[2];
  const int* pad  = (const int*)d_in[3];
  const float* Wq = (const float*)d_in[4];
  const float* bq = (const float*)d_in[5];
  const float* Wk = (const float*)d_in[6];
  const float* bk = (const float*)d_in[7];
  const float* Wv = (const float*)d_in[8];
  const float* bv = (const float*)d_in[9];
  const float* Wo = (const float*)d_in[10];
  const float* bo = (const float*)d_in[11];

  u16* ws  = (u16*)d_ws;
  u16* WoT = ws + 3 * (size_t)(1u << 20);
  u16* qb  = ws + 4 * (size_t)(1u << 20);
  u16* kb  = ws + 8 * (size_t)(1u << 20);
  u16* vb  = ws + 12 * (size_t)(1u << 20);
  u16* vTb = ws + 16 * (size_t)(1u << 20);
  u16* Abf = ws + 20 * (size_t)(1u << 20);
  u16* ao  = vb;
  float* colsumg = (float*)(ws + (1u << 20));  // WkT region dead after qkv

  const bool big = ws_size >= (size_t)64 * 1024 * 1024;

  wtrans_kernel<<<dim3(16, 16, 4), 256, 0, stream>>>(Wq, Wk, Wv, Wo, ws);
  if (big) {
    cvt_kernel<<<dim3(2048, 3), 256, 0, stream>>>(Q, Kk, V, Abf);
    qkv_gemm_b16<<<768, 256, 0, stream>>>(Abf, ws, bq, bk, bv, ws);
  } else {
    qkv_gemm_f32<<<dim3(8, 32, 3), 256, 0, stream>>>(Q, Kk, V, ws, bq, bk, bv, ws);
  }
  hipMemsetAsync(colsumg, 0, 32 * 64 * sizeof(float), stream);
  vtrans_kernel<<<dim3(32, 32), 256, 0, stream>>>(vb, vTb, colsumg);
  attn_kernel<<<512, 256, 0, stream>>>(qb, kb, vTb, pad, colsumg, ao);
  out_gemm<<<256, 256, 0, stream>>>(ao, WoT, bo, d_out);
}

// Round 9
// 134.680 us; speedup vs baseline: 2.5380x; 1.0123x over previous
//
#include <hip/hip_runtime.h>

typedef unsigned short u16;
typedef unsigned int u32;

typedef __attribute__((ext_vector_type(8))) short bfrag;   // 8 bf16 for MFMA A/B
typedef __attribute__((ext_vector_type(4))) float f32x4;
typedef __attribute__((ext_vector_type(8))) u16 u16x8;
typedef __attribute__((ext_vector_type(4))) u16 u16x4;

constexpr int S = 2048;
constexpr int HN = 16;
constexpr float QSCALE = 0.18033688011112042f;  // 0.125 * log2(e)
constexpr float NBIG   = -1.442695e9f;          // -1e9 * log2(e)

__device__ __forceinline__ u16 f2b(float f) {
  u32 u = __builtin_bit_cast(u32, f);
  return (u16)((u + 0x7FFFu + ((u >> 16) & 1u)) >> 16);  // RNE f32->bf16
}
__device__ __forceinline__ float b2f(u16 v) {
  u32 u = (u32)v << 16;
  return __builtin_bit_cast(float, u);
}
__device__ __forceinline__ u32 cvtpk(float lo, float hi) {
  u32 d;
  asm("v_cvt_pk_bf16_f32 %0, %1, %2" : "=v"(d) : "v"(lo), "v"(hi));
  return d;
}
__device__ __forceinline__ float fexp2(float x) { return __builtin_amdgcn_exp2f(x); }

__device__ __forceinline__ f32x4 mfma16(bfrag a, bfrag b, f32x4 c) {
  return __builtin_amdgcn_mfma_f32_16x16x32_bf16(a, b, c, 0, 0, 0);
}

__device__ __forceinline__ void gload_lds16(const void* g, void* l) {
  __builtin_amdgcn_global_load_lds(
      (const __attribute__((address_space(1))) u32*)g,
      (__attribute__((address_space(3))) u32*)l, 16, 0, 0);
}

// ---------------- W transpose + f32->bf16 (+ exp2-domain scale for Wq) ----------------
__global__ __launch_bounds__(256) void wtrans_kernel(
    const float* __restrict__ W0, const float* __restrict__ W1,
    const float* __restrict__ W2, const float* __restrict__ W3,
    u16* __restrict__ ws)
{
  const float* W = blockIdx.z == 0 ? W0 : blockIdx.z == 1 ? W1 : blockIdx.z == 2 ? W2 : W3;
  const float sc = blockIdx.z == 0 ? QSCALE : 1.0f;
  u16* WT = ws + (size_t)blockIdx.z * (1u << 20);
  __shared__ u16 tile[64 * 65];
  const int t = threadIdx.x;
  const int k0 = blockIdx.y * 64, n0 = blockIdx.x * 64;
#pragma unroll
  for (int i = 0; i < 4; ++i) {
    int idx = i * 256 + t;
    int r = idx >> 4, c4 = (idx & 15) * 4;
    float4 v = *(const float4*)&W[(size_t)(k0 + r) * 1024 + n0 + c4];
    tile[r * 65 + c4 + 0] = f2b(v.x * sc);
    tile[r * 65 + c4 + 1] = f2b(v.y * sc);
    tile[r * 65 + c4 + 2] = f2b(v.z * sc);
    tile[r * 65 + c4 + 3] = f2b(v.w * sc);
  }
  __syncthreads();
#pragma unroll
  for (int i = 0; i < 2; ++i) {
    int idx = i * 256 + t;
    int n = idx >> 3, k8 = (idx & 7) * 8;
    u16x8 o;
#pragma unroll
    for (int j = 0; j < 8; ++j) o[j] = tile[(k8 + j) * 65 + n];
    *(u16x8*)&WT[(size_t)(n0 + n) * 1024 + k0 + k8] = o;
  }
}

// ---------------- f32 -> bf16 bulk convert (Q, K, V inputs) ----------------
__global__ __launch_bounds__(256) void cvt_kernel(
    const float* __restrict__ A0, const float* __restrict__ A1,
    const float* __restrict__ A2, u16* __restrict__ outbase)
{
  const float* A = blockIdx.y == 0 ? A0 : blockIdx.y == 1 ? A1 : A2;
  u16* dst = outbase + (size_t)blockIdx.y * (4u << 20);
  size_t i = ((size_t)blockIdx.x * 256 + threadIdx.x) * 8;
  float4 v0 = *(const float4*)&A[i];
  float4 v1 = *(const float4*)&A[i + 4];
  union { u32 w[4]; u16x8 v; } o;
  o.w[0] = cvtpk(v0.x, v0.y); o.w[1] = cvtpk(v0.z, v0.w);
  o.w[2] = cvtpk(v1.x, v1.y); o.w[3] = cvtpk(v1.z, v1.w);
  *(u16x8*)&dst[i] = o.v;
}

// ---------------- prefix scan of pad: compact indices + per-qtile counts ----------------
// idxc[b][j] = orig position of j-th unmasked key (0x7FFF padding); eqt[b][qt] = count
// of unmasked keys with orig <= qt*64+63.
__global__ __launch_bounds__(256) void pscan_kernel(
    const int* __restrict__ pad, u16* __restrict__ idxc, int* __restrict__ eqt)
{
  __shared__ int wtot[4];
  __shared__ int cntS;
  const int b = blockIdx.x;
  const int t = threadIdx.x, lane = t & 63, w = t >> 6;
  int4 p0 = *(const int4*)&pad[b * 2048 + t * 8];
  int4 p1 = *(const int4*)&pad[b * 2048 + t * 8 + 4];
  int u[8] = {p0.x == 0, p0.y == 0, p0.z == 0, p0.w == 0,
              p1.x == 0, p1.y == 0, p1.z == 0, p1.w == 0};
  int ps[8], run = 0;
#pragma unroll
  for (int j = 0; j < 8; ++j) { run += u[j]; ps[j] = run; }
  int sc = run;
#pragma unroll
  for (int o = 1; o < 64; o <<= 1) {
    int v = __shfl_up(sc, o);
    if (lane >= o) sc += v;
  }
  if (lane == 63) wtot[w] = sc;
  __syncthreads();
  int base = 0;
#pragma unroll
  for (int i = 0; i < 4; ++i) if (i < w) base += wtot[i];
  int excl = base + sc - run;
#pragma unroll
  for (int j = 0; j < 8; ++j)
    if (u[j]) idxc[b * 2048 + excl + ps[j] - 1] = (u16)(t * 8 + j);
  if ((t & 7) == 7) eqt[b * 32 + (t >> 3)] = base + sc;
  if (t == 255) cntS = base + sc;
  __syncthreads();
  for (int j = cntS + t; j < 2048; j += 256) idxc[b * 2048 + j] = 0x7FFF;
}

// ---------------- column sum of v over ALL rows (for fully-masked-row fixup) ----------
__global__ __launch_bounds__(256) void colsum_kernel(
    const u16* __restrict__ v, float* __restrict__ colsumg)
{
  const int bh = blockIdx.x >> 3, seg = blockIdx.x & 7;
  const int t = threadIdx.x;
  const int c8 = t & 7, rq = t >> 3;
  float acc[8] = {};
  for (int it = 0; it < 8; ++it) {
    int row = seg * 256 + it * 32 + rq;
    u16x8 x = *(const u16x8*)&v[((size_t)bh * 2048 + row) * 64 + c8 * 8];
#pragma unroll
    for (int j = 0; j < 8; ++j) acc[j] += b2f(x[j]);
  }
#pragma unroll
  for (int o = 8; o < 64; o <<= 1)
#pragma unroll
    for (int j = 0; j < 8; ++j) acc[j] += __shfl_xor(acc[j], o);
  if ((t & 63) < 8) {
#pragma unroll
    for (int j = 0; j < 8; ++j)
      atomicAdd(&colsumg[bh * 64 + c8 * 8 + j], acc[j]);
  }
}

// -------- gather compacted K rows (swizzle baked for attn staging) --------
__global__ __launch_bounds__(256) void kvgather_kernel(
    const u16* __restrict__ kb, const u16* __restrict__ idxc, u16* __restrict__ kc)
{
  const int ti = blockIdx.x, bh = blockIdx.y, b = bh >> 4;
  const int t = threadIdx.x;
#pragma unroll
  for (int pass = 0; pass < 2; ++pass) {
    int jl = pass * 32 + (t >> 3), db = t & 7;
    int j = ti * 64 + jl;
    int o = idxc[b * 2048 + j];
    u16x8 val = {};
    if (o != 0x7FFF)
      val = *(const u16x8*)&kb[((size_t)bh * 2048 + o) * 64 + db * 8];
    *(u16x8*)&kc[((size_t)bh * 2048 + j) * 64 + (db ^ (j & 7)) * 8] = val;
  }
}

// -------- gather compacted V rows, transpose + permute + swizzle into vTc --------
// key j (local in tile, = 32a+16b+8cc+4d+e) -> slot 32a+16cc+8d+4b+e, col = slot^((dv&7)<<3)
__global__ __launch_bounds__(256) void vgather_kernel(
    const u16* __restrict__ vb, const u16* __restrict__ idxc, u16* __restrict__ vTc)
{
  __shared__ u16 tile[64 * 65];
  const int ti = blockIdx.x, bh = blockIdx.y, b = bh >> 4;
  const int t = threadIdx.x;
#pragma unroll
  for (int i = 0; i < 2; ++i) {
    int idx = i * 256 + t;
    int r = idx >> 3, c8 = (idx & 7) * 8;
    int o = idxc[b * 2048 + ti * 64 + r];
    u16x8 in = {};
    if (o != 0x7FFF) in = *(const u16x8*)&vb[((size_t)bh * 2048 + o) * 64 + c8];
#pragma unroll
    for (int j = 0; j < 8; ++j) tile[r * 65 + c8 + j] = in[j];
  }
  __syncthreads();
#pragma unroll
  for (int i = 0; i < 2; ++i) {
    int idx = i * 256 + t;
    int dv = idx >> 3, s8 = (idx & 7) * 8;
    u16x8 o_;
#pragma unroll
    for (int j = 0; j < 8; ++j) o_[j] = tile[(s8 + j) * 65 + dv];
    int a = s8 >> 5, bb = (s8 >> 4) & 1, cc = (s8 >> 3) & 1;
    int s0l = a * 32 + cc * 16 + bb * 4;
    int x = (dv & 7) << 3;
    u16x4 lo = {o_[0], o_[1], o_[2], o_[3]};
    u16x4 hi = {o_[4], o_[5], o_[6], o_[7]};
    size_t rowbase = ((size_t)bh * 64 + dv) * S + ti * 64;
    *(u16x4*)&vTc[rowbase + (s0l ^ x)] = lo;
    *(u16x4*)&vTc[rowbase + ((s0l + 8) ^ x)] = hi;
  }
}

// ---------------- shared GEMM core: C[M,N] = A[M,K] * Bt[N,K]^T + bias*bscale ----------
template <int AMODE, int CMODE>
__device__ __forceinline__ void gemm_core(
    u16* As, u16* Bs,
    const void* __restrict__ Av, const u16* __restrict__ Bt,
    const float* __restrict__ bias, void* __restrict__ Cout,
    int N, int K, int bn, int bm, float bscale)
{
  const int tid = threadIdx.x;
  const int wid = tid >> 6, lane = tid & 63;
  const int g = lane >> 4, c = lane & 15;
  const int wr = wid >> 1, wc = wid & 1;

  f32x4 acc[4][4] = {};

  const int nkt = K >> 6;
  for (int kt = 0; kt < nkt; ++kt) {
    if (AMODE == 0) {
      const float* A = (const float*)Av;
#pragma unroll
      for (int p = 0; p < 4; ++p) {
        int e = (p * 256 + tid) * 8;
        int row = e >> 6, col = e & 63;
        const float* src = &A[(size_t)(bm * 128 + row) * K + kt * 64 + col];
        float4 v0 = *(const float4*)src;
        float4 v1 = *(const float4*)(src + 4);
        u16x8 w;
        w[0] = f2b(v0.x); w[1] = f2b(v0.y); w[2] = f2b(v0.z); w[3] = f2b(v0.w);
        w[4] = f2b(v1.x); w[5] = f2b(v1.y); w[6] = f2b(v1.z); w[7] = f2b(v1.w);
        *(u16x8*)&As[row * 64 + (col ^ ((row & 7) << 3))] = w;
      }
    } else {
      const u16* A = (const u16*)Av;
#pragma unroll
      for (int p = 0; p < 4; ++p) {
        int off = (p * 4 + wid) * 1024 + (lane << 4);
        int row = off >> 7, colb = off & 127;
        gload_lds16(&A[(size_t)(bm * 128 + row) * K + kt * 64 +
                       ((colb ^ ((row & 7) << 4)) >> 1)],
                    (char*)As + (p * 4 + wid) * 1024);
      }
    }
#pragma unroll
    for (int p = 0; p < 4; ++p) {
      int off = (p * 4 + wid) * 1024 + (lane << 4);
      int row = off >> 7, colb = off & 127;
      gload_lds16(&Bt[(size_t)(bn * 128 + row) * K + kt * 64 +
                      ((colb ^ ((row & 7) << 4)) >> 1)],
                  (char*)Bs + (p * 4 + wid) * 1024);
    }
    __syncthreads();

#pragma unroll
    for (int ks = 0; ks < 2; ++ks) {
      bfrag af[4], bf[4];
#pragma unroll
      for (int mi = 0; mi < 4; ++mi) {
        int row = wr * 64 + mi * 16 + c;
        af[mi] = *(const bfrag*)&As[row * 64 + ((ks * 32 + g * 8) ^ ((row & 7) << 3))];
      }
#pragma unroll
      for (int ni = 0; ni < 4; ++ni) {
        int row = wc * 64 + ni * 16 + c;
        bf[ni] = *(const bfrag*)&Bs[row * 64 + ((ks * 32 + g * 8) ^ ((row & 7) << 3))];
      }
#pragma unroll
      for (int mi = 0; mi < 4; ++mi)
#pragma unroll
        for (int ni = 0; ni < 4; ++ni)
          acc[mi][ni] = mfma16(af[mi], bf[ni], acc[mi][ni]);
    }
    __syncthreads();
  }

#pragma unroll
  for (int mi = 0; mi < 4; ++mi) {
#pragma unroll
    for (int ni = 0; ni < 4; ++ni) {
#pragma unroll
      for (int j = 0; j < 4; ++j) {
        int rowg = bm * 128 + wr * 64 + mi * 16 + g * 4 + j;
        int colg = bn * 128 + wc * 64 + ni * 16 + c;
        float val = fmaf(bias[colg], bscale, acc[mi][ni][j]);
        if (CMODE == 0) {
          int b = rowg >> 11, s = rowg & (S - 1);
          int h = colg >> 6, d = colg & 63;
          ((u16*)Cout)[((size_t)((b * HN + h) * S + s)) * 64 + d] = f2b(val);
        } else {
          ((float*)Cout)[(size_t)rowg * N + colg] = val;
        }
      }
    }
  }
}

__global__ __launch_bounds__(256) void qkv_gemm_b16(
    const u16* __restrict__ Abase, const u16* __restrict__ WTbase,
    const float* __restrict__ b0, const float* __restrict__ b1, const float* __restrict__ b2,
    u16* __restrict__ wsbase)
{
  __shared__ __align__(16) u16 As[128 * 64];
  __shared__ __align__(16) u16 Bs[128 * 64];
  const int bid = blockIdx.x;
  const int l = (bid & 7) * 96 + (bid >> 3);
  const int z = l >> 8, rem = l & 255, bm = rem >> 3, bn = rem & 7;
  const u16* A = Abase + (size_t)z * (4u << 20);
  const u16* Bt = WTbase + (size_t)z * (1u << 20);
  const float* bias = z == 0 ? b0 : z == 1 ? b1 : b2;
  u16* C = wsbase + (size_t)(4 + 4 * z) * (1u << 20);
  gemm_core<2, 0>(As, Bs, A, Bt, bias, C, 1024, 1024, bn, bm,
                  z == 0 ? QSCALE : 1.0f);
}

__global__ __launch_bounds__(256) void qkv_gemm_f32(
    const float* __restrict__ A0, const float* __restrict__ A1, const float* __restrict__ A2,
    const u16* __restrict__ WTbase,
    const float* __restrict__ b0, const float* __restrict__ b1, const float* __restrict__ b2,
    u16* __restrict__ wsbase)
{
  __shared__ __align__(16) u16 As[128 * 64];
  __shared__ __align__(16) u16 Bs[128 * 64];
  const int z = blockIdx.z;
  const float* A = z == 0 ? A0 : z == 1 ? A1 : A2;
  const u16* Bt = WTbase + (size_t)z * (1u << 20);
  const float* bias = z == 0 ? b0 : z == 1 ? b1 : b2;
  u16* C = wsbase + (size_t)(4 + 4 * z) * (1u << 20);
  gemm_core<0, 0>(As, Bs, A, Bt, bias, C, 1024, 1024, blockIdx.x, blockIdx.y,
                  z == 0 ? QSCALE : 1.0f);
}

__global__ __launch_bounds__(256) void out_gemm(
    const u16* __restrict__ Av, const u16* __restrict__ Bt,
    const float* __restrict__ bias, void* __restrict__ Cout)
{
  __shared__ __align__(16) u16 As[128 * 64];
  __shared__ __align__(16) u16 Bs[128 * 64];
  const int bid = blockIdx.x;
  const int l = (bid & 7) * 32 + (bid >> 3);
  const int bm = l >> 3, bn = l & 7;
  gemm_core<2, 1>(As, Bs, Av, Bt, bias, Cout, 1024, 1024, bn, bm, 1.0f);
}

// ---------------- flash attention v5: compacted keys ----------------
// 1024 blocks (one qt each, LPT order: qt=31 first), 4 waves x 16 q-rows.
// K/V staged from compacted, pre-swizzled buffers via global_load_lds, dbuf.
// Causal + tail masking via orig-index compare on boundary tiles only.
__global__ __launch_bounds__(256) void attn_kernel(
    const u16* __restrict__ q, const u16* __restrict__ kc,
    const u16* __restrict__ vTc, const u16* __restrict__ idxc,
    const int* __restrict__ eqt, const float* __restrict__ colsumg,
    u16* __restrict__ ao)
{
  __shared__ __align__(16) u16 Ks[2][64 * 64];
  __shared__ __align__(16) u16 Vs[2][64 * 64];

  const int tid = threadIdx.x;
  const int wid = tid >> 6, lane = tid & 63;
  const int g = lane >> 4, c = lane & 15;
  const int i = blockIdx.x;
  const int qt = 31 - (i >> 5);     // LPT: longest blocks dispatch first
  const int bh = i & 31;            // bh%8 stable per XCD slot
  const int b = bh >> 4, h = bh & 15;

  const u16* idxb = idxc + b * 2048;
  const int ecnt = eqt[b * 32 + qt];
  const int nt = (ecnt + 63) >> 6;
  const int fz = idxb[0];
  const int qbasew = qt * 64 + wid * 16;
  const int qrow = qbasew + c;

  bfrag qf[2];
#pragma unroll
  for (int ks = 0; ks < 2; ++ks)
    qf[ks] = *(const bfrag*)&q[((size_t)bh * S + qrow) * 64 + ks * 32 + g * 8];

  float m = -3.0e38f, lsum = 0.f;
  f32x4 acc[4] = {};

  const size_t kbase = (size_t)bh * S * 64;
  const size_t vbase = (size_t)bh * 64 * S;
  const int sb = wid * 2048 + (lane << 4);
  const int sb2 = sb + 1024;

#define STAGE(buf, t)                                                              \
  do {                                                                             \
    gload_lds16(&kc[kbase + (size_t)(t) * 4096 + (sb >> 1)],                       \
                (char*)Ks[buf] + wid * 2048);                                      \
    gload_lds16(&kc[kbase + (size_t)(t) * 4096 + (sb2 >> 1)],                      \
                (char*)Ks[buf] + wid * 2048 + 1024);                               \
    gload_lds16(&vTc[vbase + (size_t)(sb >> 7) * S + (t) * 64 + ((sb & 127) >> 1)],\
                (char*)Vs[buf] + wid * 2048);                                      \
    gload_lds16(&vTc[vbase + (size_t)(sb2 >> 7) * S + (t) * 64 + ((sb2 & 127) >> 1)],\
                (char*)Vs[buf] + wid * 2048 + 1024);                               \
  } while (0)

  if (nt > 0) {
    STAGE(0, 0);
    __syncthreads();

    int cur = 0;
    for (int t = 0; t < nt; ++t) {
      if (t + 1 < nt) { STAGE(cur ^ 1, t + 1); }

      // QK^T (swapped): D[key][qrow]; compacted keys are all unmasked -> no bias add
      f32x4 sc[4] = {};
      __builtin_amdgcn_s_setprio(1);
#pragma unroll
      for (int ks = 0; ks < 2; ++ks)
#pragma unroll
        for (int nf = 0; nf < 4; ++nf) {
          int row = nf * 16 + c;
          bfrag kf = *(const bfrag*)&Ks[cur][row * 64 + ((ks * 32 + g * 8) ^ ((row & 7) << 3))];
          sc[nf] = mfma16(kf, qf[ks], sc[nf]);
        }
      __builtin_amdgcn_s_setprio(0);

      float sval[4][4];
#pragma unroll
      for (int nf = 0; nf < 4; ++nf)
#pragma unroll
        for (int r = 0; r < 4; ++r) sval[nf][r] = sc[nf][r];

      // boundary tile (causal edge or compaction tail): mask by orig index
      if ((int)idxb[t * 64 + 63] > qbasew) {
#pragma unroll
        for (int nf = 0; nf < 4; ++nf)
#pragma unroll
          for (int r = 0; r < 4; ++r) {
            int ov = idxb[t * 64 + nf * 16 + g * 4 + r];
            if (ov > qrow) sval[nf][r] = NBIG;
          }
      }

      float pm = sval[0][0];
#pragma unroll
      for (int nf = 0; nf < 4; ++nf)
#pragma unroll
        for (int r = 0; r < 4; ++r) pm = fmaxf(pm, sval[nf][r]);
      pm = fmaxf(pm, __shfl_xor(pm, 16));
      pm = fmaxf(pm, __shfl_xor(pm, 32));
      if (!__all(pm - m <= 11.5416f)) {   // defer-max
        float mn = fmaxf(m, pm);
        float fac = fexp2(m - mn);
        lsum *= fac;
#pragma unroll
        for (int nf = 0; nf < 4; ++nf)
#pragma unroll
          for (int j = 0; j < 4; ++j) acc[nf][j] *= fac;
        m = mn;
      }
      float p16v[4][4];
      float rs = 0.f;
#pragma unroll
      for (int nf = 0; nf < 4; ++nf)
#pragma unroll
        for (int r = 0; r < 4; ++r) {
          float pv = fexp2(sval[nf][r] - m);
          p16v[nf][r] = pv;
          rs += pv;
        }
      rs += __shfl_xor(rs, 16);
      rs += __shfl_xor(rs, 32);
      lsum += rs;

      bfrag pa[2];
#pragma unroll
      for (int ks = 0; ks < 2; ++ks) {
        union { u32 w[4]; bfrag f; } pu;
#pragma unroll
        for (int tt = 0; tt < 4; ++tt)
          pu.w[tt] = cvtpk(p16v[2 * ks + (tt >> 1)][2 * (tt & 1)],
                           p16v[2 * ks + (tt >> 1)][2 * (tt & 1) + 1]);
        pa[ks] = pu.f;
      }

      // PV (swapped): D[dv][qrow]
      __builtin_amdgcn_s_setprio(1);
#pragma unroll
      for (int ks = 0; ks < 2; ++ks)
#pragma unroll
        for (int nf = 0; nf < 4; ++nf) {
          int row = nf * 16 + c;
          bfrag vf = *(const bfrag*)&Vs[cur][row * 64 + ((ks * 32 + g * 8) ^ ((row & 7) << 3))];
          acc[nf] = mfma16(vf, pa[ks], acc[nf]);
        }
      __builtin_amdgcn_s_setprio(0);

      __syncthreads();
      cur ^= 1;
    }
  }
#undef STAGE

  // epilogue (+ fused fully-masked-row fixup: uniform over all 2048 keys)
  const float inv = 1.f / lsum;
#pragma unroll
  for (int nf = 0; nf < 4; ++nf) {
    u16x4 ov;
    if (qrow < fz) {
#pragma unroll
      for (int j = 0; j < 4; ++j)
        ov[j] = f2b(colsumg[bh * 64 + nf * 16 + g * 4 + j] * (1.f / 2048.f));
    } else {
#pragma unroll
      for (int j = 0; j < 4; ++j) ov[j] = f2b(acc[nf][j] * inv);
    }
    *(u16x4*)&ao[((size_t)b * S + qrow) * 1024 + h * 64 + nf * 16 + g * 4] = ov;
  }
}

// ---------------- launch ----------------
extern "C" void kernel_launch(void* const* d_in, const int* in_sizes, int n_in,
                              void* d_out, int out_size, void* d_ws, size_t ws_size,
                              hipStream_t stream)
{
  const float* Q  = (const float*)d_in[0];
  const float* Kk = (const float*)d_in[1];
  const float* V  = (const float*)d_in[2];
  const int* pad  = (const int*)d_in[3];
  const float* Wq = (const float*)d_in[4];
  const float* bq = (const float*)d_in[5];
  const float* Wk = (const float*)d_in[6];
  const float* bk = (const float*)d_in[7];
  const float* Wv = (const float*)d_in[8];
  const float* bv = (const float*)d_in[9];
  const float* Wo = (const float*)d_in[10];
  const float* bo = (const float*)d_in[11];

  // ws layout (u16 elems):
  // [0,4M): 4x WT | [4M,8M): q | [8M,12M): k | [12M,16M): v/ao | [16M,20M): vT(unused)
  // [20M,32M): Abf (cvt) -> after qkv reused: kc [20M,24M), vTc [24M,28M)
  // WkT region [1M,2M) after qkv: colsumg (4096 u16) | idxc (4096 u16) | eqt
  u16* ws  = (u16*)d_ws;
  u16* WoT = ws + 3 * (size_t)(1u << 20);
  u16* qb  = ws + 4 * (size_t)(1u << 20);
  u16* kb  = ws + 8 * (size_t)(1u << 20);
  u16* vb  = ws + 12 * (size_t)(1u << 20);
  u16* Abf = ws + 20 * (size_t)(1u << 20);
  u16* kc  = ws + 20 * (size_t)(1u << 20);
  u16* vTc = ws + 24 * (size_t)(1u << 20);
  u16* ao  = vb;
  float* colsumg = (float*)(ws + (1u << 20));
  u16* idxc = ws + (1u << 20) + 4096;
  int* eqt  = (int*)(ws + (1u << 20) + 8192);

  const bool big = ws_size >= (size_t)64 * 1024 * 1024;

  wtrans_kernel<<<dim3(16, 16, 4), 256, 0, stream>>>(Wq, Wk, Wv, Wo, ws);
  if (big) {
    cvt_kernel<<<dim3(2048, 3), 256, 0, stream>>>(Q, Kk, V, Abf);
    qkv_gemm_b16<<<768, 256, 0, stream>>>(Abf, ws, bq, bk, bv, ws);
  } else {
    qkv_gemm_f32<<<dim3(8, 32, 3), 256, 0, stream>>>(Q, Kk, V, ws, bq, bk, bv, ws);
  }
  hipMemsetAsync(colsumg, 0, 32 * 64 * sizeof(float), stream);
  pscan_kernel<<<2, 256, 0, stream>>>(pad, idxc, eqt);
  colsum_kernel<<<256, 256, 0, stream>>>(vb, colsumg);
  kvgather_kernel<<<dim3(32, 32), 256, 0, stream>>>(kb, idxc, kc);
  vgather_kernel<<<dim3(32, 32), 256, 0, stream>>>(vb, idxc, vTc);
  attn_kernel<<<1024, 256, 0, stream>>>(qb, kc, vTc, idxc, eqt, colsumg, ao);
  out_gemm<<<256, 256, 0, stream>>>(ao, WoT, bo, d_out);
}

// Round 10
// 116.680 us; speedup vs baseline: 2.9295x; 1.1543x over previous
//
#include <hip/hip_runtime.h>

typedef unsigned short u16;
typedef unsigned int u32;

typedef __attribute__((ext_vector_type(8))) short bfrag;   // 8 bf16 for MFMA A/B
typedef __attribute__((ext_vector_type(4))) float f32x4;
typedef __attribute__((ext_vector_type(8))) u16 u16x8;
typedef __attribute__((ext_vector_type(4))) u16 u16x4;

constexpr int S = 2048;
constexpr int HN = 16;
constexpr float QSCALE = 0.18033688011112042f;  // 0.125 * log2(e)
constexpr float NBIG   = -1.442695e9f;          // -1e9 * log2(e)

__device__ __forceinline__ u16 f2b(float f) {
  u32 u = __builtin_bit_cast(u32, f);
  return (u16)((u + 0x7FFFu + ((u >> 16) & 1u)) >> 16);  // RNE f32->bf16
}
__device__ __forceinline__ float b2f(u16 v) {
  u32 u = (u32)v << 16;
  return __builtin_bit_cast(float, u);
}
__device__ __forceinline__ u32 cvtpk(float lo, float hi) {
  u32 d;
  asm("v_cvt_pk_bf16_f32 %0, %1, %2" : "=v"(d) : "v"(lo), "v"(hi));
  return d;
}
__device__ __forceinline__ float fexp2(float x) { return __builtin_amdgcn_exp2f(x); }

__device__ __forceinline__ f32x4 mfma16(bfrag a, bfrag b, f32x4 c) {
  return __builtin_amdgcn_mfma_f32_16x16x32_bf16(a, b, c, 0, 0, 0);
}

__device__ __forceinline__ void gload_lds16(const void* g, void* l) {
  __builtin_amdgcn_global_load_lds(
      (const __attribute__((address_space(1))) u32*)g,
      (__attribute__((address_space(3))) u32*)l, 16, 0, 0);
}

// ---------------- W transpose + f32->bf16 (+ exp2-domain scale for Wq) ----------------
__global__ __launch_bounds__(256) void wtrans_kernel(
    const float* __restrict__ W0, const float* __restrict__ W1,
    const float* __restrict__ W2, const float* __restrict__ W3,
    u16* __restrict__ ws)
{
  const float* W = blockIdx.z == 0 ? W0 : blockIdx.z == 1 ? W1 : blockIdx.z == 2 ? W2 : W3;
  const float sc = blockIdx.z == 0 ? QSCALE : 1.0f;
  u16* WT = ws + (size_t)blockIdx.z * (1u << 20);
  __shared__ u16 tile[64 * 65];
  const int t = threadIdx.x;
  const int k0 = blockIdx.y * 64, n0 = blockIdx.x * 64;
#pragma unroll
  for (int i = 0; i < 4; ++i) {
    int idx = i * 256 + t;
    int r = idx >> 4, c4 = (idx & 15) * 4;
    float4 v = *(const float4*)&W[(size_t)(k0 + r) * 1024 + n0 + c4];
    tile[r * 65 + c4 + 0] = f2b(v.x * sc);
    tile[r * 65 + c4 + 1] = f2b(v.y * sc);
    tile[r * 65 + c4 + 2] = f2b(v.z * sc);
    tile[r * 65 + c4 + 3] = f2b(v.w * sc);
  }
  __syncthreads();
#pragma unroll
  for (int i = 0; i < 2; ++i) {
    int idx = i * 256 + t;
    int n = idx >> 3, k8 = (idx & 7) * 8;
    u16x8 o;
#pragma unroll
    for (int j = 0; j < 8; ++j) o[j] = tile[(k8 + j) * 65 + n];
    *(u16x8*)&WT[(size_t)(n0 + n) * 1024 + k0 + k8] = o;
  }
}

// ---------------- f32 -> bf16 bulk convert (Q, K, V inputs) ----------------
__global__ __launch_bounds__(256) void cvt_kernel(
    const float* __restrict__ A0, const float* __restrict__ A1,
    const float* __restrict__ A2, u16* __restrict__ outbase)
{
  const float* A = blockIdx.y == 0 ? A0 : blockIdx.y == 1 ? A1 : A2;
  u16* dst = outbase + (size_t)blockIdx.y * (4u << 20);
  size_t i = ((size_t)blockIdx.x * 256 + threadIdx.x) * 8;
  float4 v0 = *(const float4*)&A[i];
  float4 v1 = *(const float4*)&A[i + 4];
  union { u32 w[4]; u16x8 v; } o;
  o.w[0] = cvtpk(v0.x, v0.y); o.w[1] = cvtpk(v0.z, v0.w);
  o.w[2] = cvtpk(v1.x, v1.y); o.w[3] = cvtpk(v1.z, v1.w);
  *(u16x8*)&dst[i] = o.v;
}

// ---------------- prefix scan of pad: compact indices + counts (+ zero colsumg) ------
__global__ __launch_bounds__(256) void pscan_kernel(
    const int* __restrict__ pad, u16* __restrict__ idxc, int* __restrict__ eqt,
    float* __restrict__ colsumg)
{
  __shared__ int wtot[4];
  __shared__ int cntS;
  const int b = blockIdx.x;
  const int t = threadIdx.x, lane = t & 63, w = t >> 6;
  for (int i = t; i < 1024; i += 256) colsumg[b * 1024 + i] = 0.f;
  int4 p0 = *(const int4*)&pad[b * 2048 + t * 8];
  int4 p1 = *(const int4*)&pad[b * 2048 + t * 8 + 4];
  int u[8] = {p0.x == 0, p0.y == 0, p0.z == 0, p0.w == 0,
              p1.x == 0, p1.y == 0, p1.z == 0, p1.w == 0};
  int ps[8], run = 0;
#pragma unroll
  for (int j = 0; j < 8; ++j) { run += u[j]; ps[j] = run; }
  int sc = run;
#pragma unroll
  for (int o = 1; o < 64; o <<= 1) {
    int v = __shfl_up(sc, o);
    if (lane >= o) sc += v;
  }
  if (lane == 63) wtot[w] = sc;
  __syncthreads();
  int base = 0;
#pragma unroll
  for (int i = 0; i < 4; ++i) if (i < w) base += wtot[i];
  int excl = base + sc - run;
#pragma unroll
  for (int j = 0; j < 8; ++j)
    if (u[j]) idxc[b * 2048 + excl + ps[j] - 1] = (u16)(t * 8 + j);
  if ((t & 7) == 7) eqt[b * 32 + (t >> 3)] = base + sc;
  if (t == 255) cntS = base + sc;
  __syncthreads();
  for (int j = cntS + t; j < 2048; j += 256) idxc[b * 2048 + j] = 0x7FFF;
}

// ---------------- column sum of v over ALL rows (for fully-masked-row fixup) ----------
__global__ __launch_bounds__(256) void colsum_kernel(
    const u16* __restrict__ v, float* __restrict__ colsumg)
{
  const int bh = blockIdx.x >> 3, seg = blockIdx.x & 7;
  const int t = threadIdx.x;
  const int c8 = t & 7, rq = t >> 3;
  float acc[8] = {};
  for (int it = 0; it < 8; ++it) {
    int row = seg * 256 + it * 32 + rq;
    u16x8 x = *(const u16x8*)&v[((size_t)bh * 2048 + row) * 64 + c8 * 8];
#pragma unroll
    for (int j = 0; j < 8; ++j) acc[j] += b2f(x[j]);
  }
#pragma unroll
  for (int o = 8; o < 64; o <<= 1)
#pragma unroll
    for (int j = 0; j < 8; ++j) acc[j] += __shfl_xor(acc[j], o);
  if ((t & 63) < 8) {
#pragma unroll
    for (int j = 0; j < 8; ++j)
      atomicAdd(&colsumg[bh * 64 + c8 * 8 + j], acc[j]);
  }
}

// -------- fused gather: compacted K rows (swizzled) + V transpose/permute/swizzle ------
__global__ __launch_bounds__(256) void kvgather_kernel(
    const u16* __restrict__ kb, const u16* __restrict__ vb,
    const u16* __restrict__ idxc, u16* __restrict__ kc, u16* __restrict__ vTc)
{
  __shared__ u16 tile[64 * 65];
  const int ti = blockIdx.x, bh = blockIdx.y, b = bh >> 4;
  const int t = threadIdx.x;

  // --- K gather (row-wise, swizzle baked for attn staging) ---
#pragma unroll
  for (int pass = 0; pass < 2; ++pass) {
    int jl = pass * 32 + (t >> 3), db = t & 7;
    int j = ti * 64 + jl;
    int o = idxc[b * 2048 + j];
    u16x8 val = {};
    if (o != 0x7FFF)
      val = *(const u16x8*)&kb[((size_t)bh * 2048 + o) * 64 + db * 8];
    *(u16x8*)&kc[((size_t)bh * 2048 + j) * 64 + (db ^ (j & 7)) * 8] = val;
  }

  // --- V gather + transpose (key j = 32a+16b+8cc+4d+e -> slot 32a+16cc+8d+4b+e) ---
#pragma unroll
  for (int i = 0; i < 2; ++i) {
    int idx = i * 256 + t;
    int r = idx >> 3, c8 = (idx & 7) * 8;
    int o = idxc[b * 2048 + ti * 64 + r];
    u16x8 in = {};
    if (o != 0x7FFF) in = *(const u16x8*)&vb[((size_t)bh * 2048 + o) * 64 + c8];
#pragma unroll
    for (int j = 0; j < 8; ++j) tile[r * 65 + c8 + j] = in[j];
  }
  __syncthreads();
#pragma unroll
  for (int i = 0; i < 2; ++i) {
    int idx = i * 256 + t;
    int dv = idx >> 3, s8 = (idx & 7) * 8;
    u16x8 o_;
#pragma unroll
    for (int j = 0; j < 8; ++j) o_[j] = tile[(s8 + j) * 65 + dv];
    int a = s8 >> 5, bb = (s8 >> 4) & 1, cc = (s8 >> 3) & 1;
    int s0l = a * 32 + cc * 16 + bb * 4;
    int x = (dv & 7) << 3;
    u16x4 lo = {o_[0], o_[1], o_[2], o_[3]};
    u16x4 hi = {o_[4], o_[5], o_[6], o_[7]};
    size_t rowbase = ((size_t)bh * 64 + dv) * S + ti * 64;
    *(u16x4*)&vTc[rowbase + (s0l ^ x)] = lo;
    *(u16x4*)&vTc[rowbase + ((s0l + 8) ^ x)] = hi;
  }
}

// ------- shared GEMM core, 128(M) x 64(N) tile: C = A[M,K]*Bt[N,K]^T + bias*bscale ----
// AMODE 0: A f32 reg-staged (convert to bf16); 2: A bf16 via global_load_lds.
// CMODE 0: scatter-store bf16 to [B,H,S,64]; 1: f32 linear [M,N].
template <int AMODE, int CMODE>
__device__ __forceinline__ void gemm_core(
    u16* As, u16* Bs,
    const void* __restrict__ Av, const u16* __restrict__ Bt,
    const float* __restrict__ bias, void* __restrict__ Cout,
    int N, int K, int bn, int bm, float bscale)
{
  const int tid = threadIdx.x;
  const int wid = tid >> 6, lane = tid & 63;
  const int g = lane >> 4, c = lane & 15;
  const int wr = wid >> 1, wc = wid & 1;

  f32x4 acc[4][2] = {};

  const int nkt = K >> 6;
  for (int kt = 0; kt < nkt; ++kt) {
    if (AMODE == 0) {
      const float* A = (const float*)Av;
#pragma unroll
      for (int p = 0; p < 4; ++p) {
        int e = (p * 256 + tid) * 8;
        int row = e >> 6, col = e & 63;
        const float* src = &A[(size_t)(bm * 128 + row) * K + kt * 64 + col];
        float4 v0 = *(const float4*)src;
        float4 v1 = *(const float4*)(src + 4);
        u16x8 w;
        w[0] = f2b(v0.x); w[1] = f2b(v0.y); w[2] = f2b(v0.z); w[3] = f2b(v0.w);
        w[4] = f2b(v1.x); w[5] = f2b(v1.y); w[6] = f2b(v1.z); w[7] = f2b(v1.w);
        *(u16x8*)&As[row * 64 + (col ^ ((row & 7) << 3))] = w;
      }
    } else {
      const u16* A = (const u16*)Av;
#pragma unroll
      for (int p = 0; p < 4; ++p) {
        int off = (p * 4 + wid) * 1024 + (lane << 4);
        int row = off >> 7, colb = off & 127;
        gload_lds16(&A[(size_t)(bm * 128 + row) * K + kt * 64 +
                       ((colb ^ ((row & 7) << 4)) >> 1)],
                    (char*)As + (p * 4 + wid) * 1024);
      }
    }
    // B tile: 64 rows x 64 cols = 8 KB = 2 issue rounds
#pragma unroll
    for (int p = 0; p < 2; ++p) {
      int off = (p * 4 + wid) * 1024 + (lane << 4);
      int row = off >> 7, colb = off & 127;
      gload_lds16(&Bt[(size_t)(bn * 64 + row) * K + kt * 64 +
                      ((colb ^ ((row & 7) << 4)) >> 1)],
                  (char*)Bs + (p * 4 + wid) * 1024);
    }
    __syncthreads();

#pragma unroll
    for (int ks = 0; ks < 2; ++ks) {
      bfrag af[4], bf[2];
#pragma unroll
      for (int mi = 0; mi < 4; ++mi) {
        int row = wr * 64 + mi * 16 + c;
        af[mi] = *(const bfrag*)&As[row * 64 + ((ks * 32 + g * 8) ^ ((row & 7) << 3))];
      }
#pragma unroll
      for (int ni = 0; ni < 2; ++ni) {
        int row = wc * 32 + ni * 16 + c;
        bf[ni] = *(const bfrag*)&Bs[row * 64 + ((ks * 32 + g * 8) ^ ((row & 7) << 3))];
      }
#pragma unroll
      for (int mi = 0; mi < 4; ++mi)
#pragma unroll
        for (int ni = 0; ni < 2; ++ni)
          acc[mi][ni] = mfma16(af[mi], bf[ni], acc[mi][ni]);
    }
    __syncthreads();
  }

#pragma unroll
  for (int mi = 0; mi < 4; ++mi) {
#pragma unroll
    for (int ni = 0; ni < 2; ++ni) {
#pragma unroll
      for (int j = 0; j < 4; ++j) {
        int rowg = bm * 128 + wr * 64 + mi * 16 + g * 4 + j;
        int colg = bn * 64 + wc * 32 + ni * 16 + c;
        float val = fmaf(bias[colg], bscale, acc[mi][ni][j]);
        if (CMODE == 0) {
          int b = rowg >> 11, s = rowg & (S - 1);
          int h = colg >> 6, d = colg & 63;
          ((u16*)Cout)[((size_t)((b * HN + h) * S + s)) * 64 + d] = f2b(val);
        } else {
          ((float*)Cout)[(size_t)rowg * N + colg] = val;
        }
      }
    }
  }
}

// pure-bf16 QKV projection, 1D grid 1536 (6 blocks/CU queued), XCD-chunked decode
__global__ __launch_bounds__(256) void qkv_gemm_b16(
    const u16* __restrict__ Abase, const u16* __restrict__ WTbase,
    const float* __restrict__ b0, const float* __restrict__ b1, const float* __restrict__ b2,
    u16* __restrict__ wsbase)
{
  __shared__ __align__(16) u16 As[128 * 64];
  __shared__ __align__(16) u16 Bs[64 * 64];
  const int bid = blockIdx.x;
  const int l = (bid & 7) * 192 + (bid >> 3);   // each XCD owns 192 contiguous logical ids
  const int z = l >> 9, rem = l & 511, bm = rem >> 4, bn = rem & 15;
  const u16* A = Abase + (size_t)z * (4u << 20);
  const u16* Bt = WTbase + (size_t)z * (1u << 20);
  const float* bias = z == 0 ? b0 : z == 1 ? b1 : b2;
  u16* C = wsbase + (size_t)(4 + 4 * z) * (1u << 20);
  gemm_core<2, 0>(As, Bs, A, Bt, bias, C, 1024, 1024, bn, bm,
                  z == 0 ? QSCALE : 1.0f);
}

__global__ __launch_bounds__(256) void qkv_gemm_f32(
    const float* __restrict__ A0, const float* __restrict__ A1, const float* __restrict__ A2,
    const u16* __restrict__ WTbase,
    const float* __restrict__ b0, const float* __restrict__ b1, const float* __restrict__ b2,
    u16* __restrict__ wsbase)
{
  __shared__ __align__(16) u16 As[128 * 64];
  __shared__ __align__(16) u16 Bs[64 * 64];
  const int z = blockIdx.z;
  const float* A = z == 0 ? A0 : z == 1 ? A1 : A2;
  const u16* Bt = WTbase + (size_t)z * (1u << 20);
  const float* bias = z == 0 ? b0 : z == 1 ? b1 : b2;
  u16* C = wsbase + (size_t)(4 + 4 * z) * (1u << 20);
  gemm_core<0, 0>(As, Bs, A, Bt, bias, C, 1024, 1024, blockIdx.x, blockIdx.y,
                  z == 0 ? QSCALE : 1.0f);
}

__global__ __launch_bounds__(256) void out_gemm(
    const u16* __restrict__ Av, const u16* __restrict__ Bt,
    const float* __restrict__ bias, void* __restrict__ Cout)
{
  __shared__ __align__(16) u16 As[128 * 64];
  __shared__ __align__(16) u16 Bs[64 * 64];
  const int bid = blockIdx.x;
  const int l = (bid & 7) * 64 + (bid >> 3);    // 512 blocks, XCD-chunked
  const int bm = l >> 4, bn = l & 15;
  gemm_core<2, 1>(As, Bs, Av, Bt, bias, Cout, 1024, 1024, bn, bm, 1.0f);
}

// ---------------- flash attention v5: compacted keys ----------------
__global__ __launch_bounds__(256) void attn_kernel(
    const u16* __restrict__ q, const u16* __restrict__ kc,
    const u16* __restrict__ vTc, const u16* __restrict__ idxc,
    const int* __restrict__ eqt, const float* __restrict__ colsumg,
    u16* __restrict__ ao)
{
  __shared__ __align__(16) u16 Ks[2][64 * 64];
  __shared__ __align__(16) u16 Vs[2][64 * 64];

  const int tid = threadIdx.x;
  const int wid = tid >> 6, lane = tid & 63;
  const int g = lane >> 4, c = lane & 15;
  const int i = blockIdx.x;
  const int qt = 31 - (i >> 5);     // LPT: longest blocks dispatch first
  const int bh = i & 31;
  const int b = bh >> 4, h = bh & 15;

  const u16* idxb = idxc + b * 2048;
  const int ecnt = eqt[b * 32 + qt];
  const int nt = (ecnt + 63) >> 6;
  const int fz = idxb[0];
  const int qbasew = qt * 64 + wid * 16;
  const int qrow = qbasew + c;

  bfrag qf[2];
#pragma unroll
  for (int ks = 0; ks < 2; ++ks)
    qf[ks] = *(const bfrag*)&q[((size_t)bh * S + qrow) * 64 + ks * 32 + g * 8];

  float m = -3.0e38f, lsum = 0.f;
  f32x4 acc[4] = {};

  const size_t kbase = (size_t)bh * S * 64;
  const size_t vbase = (size_t)bh * 64 * S;
  const int sb = wid * 2048 + (lane << 4);
  const int sb2 = sb + 1024;

#define STAGE(buf, t)                                                              \
  do {                                                                             \
    gload_lds16(&kc[kbase + (size_t)(t) * 4096 + (sb >> 1)],                       \
                (char*)Ks[buf] + wid * 2048);                                      \
    gload_lds16(&kc[kbase + (size_t)(t) * 4096 + (sb2 >> 1)],                      \
                (char*)Ks[buf] + wid * 2048 + 1024);                               \
    gload_lds16(&vTc[vbase + (size_t)(sb >> 7) * S + (t) * 64 + ((sb & 127) >> 1)],\
                (char*)Vs[buf] + wid * 2048);                                      \
    gload_lds16(&vTc[vbase + (size_t)(sb2 >> 7) * S + (t) * 64 + ((sb2 & 127) >> 1)],\
                (char*)Vs[buf] + wid * 2048 + 1024);                               \
  } while (0)

  if (nt > 0) {
    STAGE(0, 0);
    __syncthreads();

    int cur = 0;
    for (int t = 0; t < nt; ++t) {
      if (t + 1 < nt) { STAGE(cur ^ 1, t + 1); }

      f32x4 sc[4] = {};
      __builtin_amdgcn_s_setprio(1);
#pragma unroll
      for (int ks = 0; ks < 2; ++ks)
#pragma unroll
        for (int nf = 0; nf < 4; ++nf) {
          int row = nf * 16 + c;
          bfrag kf = *(const bfrag*)&Ks[cur][row * 64 + ((ks * 32 + g * 8) ^ ((row & 7) << 3))];
          sc[nf] = mfma16(kf, qf[ks], sc[nf]);
        }
      __builtin_amdgcn_s_setprio(0);

      float sval[4][4];
#pragma unroll
      for (int nf = 0; nf < 4; ++nf)
#pragma unroll
        for (int r = 0; r < 4; ++r) sval[nf][r] = sc[nf][r];

      if ((int)idxb[t * 64 + 63] > qbasew) {
#pragma unroll
        for (int nf = 0; nf < 4; ++nf)
#pragma unroll
          for (int r = 0; r < 4; ++r) {
            int ov = idxb[t * 64 + nf * 16 + g * 4 + r];
            if (ov > qrow) sval[nf][r] = NBIG;
          }
      }

      float pm = sval[0][0];
#pragma unroll
      for (int nf = 0; nf < 4; ++nf)
#pragma unroll
        for (int r = 0; r < 4; ++r) pm = fmaxf(pm, sval[nf][r]);
      pm = fmaxf(pm, __shfl_xor(pm, 16));
      pm = fmaxf(pm, __shfl_xor(pm, 32));
      if (!__all(pm - m <= 11.5416f)) {   // defer-max
        float mn = fmaxf(m, pm);
        float fac = fexp2(m - mn);
        lsum *= fac;
#pragma unroll
        for (int nf = 0; nf < 4; ++nf)
#pragma unroll
          for (int j = 0; j < 4; ++j) acc[nf][j] *= fac;
        m = mn;
      }
      float p16v[4][4];
      float rs = 0.f;
#pragma unroll
      for (int nf = 0; nf < 4; ++nf)
#pragma unroll
        for (int r = 0; r < 4; ++r) {
          float pv = fexp2(sval[nf][r] - m);
          p16v[nf][r] = pv;
          rs += pv;
        }
      rs += __shfl_xor(rs, 16);
      rs += __shfl_xor(rs, 32);
      lsum += rs;

      bfrag pa[2];
#pragma unroll
      for (int ks = 0; ks < 2; ++ks) {
        union { u32 w[4]; bfrag f; } pu;
#pragma unroll
        for (int tt = 0; tt < 4; ++tt)
          pu.w[tt] = cvtpk(p16v[2 * ks + (tt >> 1)][2 * (tt & 1)],
                           p16v[2 * ks + (tt >> 1)][2 * (tt & 1) + 1]);
        pa[ks] = pu.f;
      }

      __builtin_amdgcn_s_setprio(1);
#pragma unroll
      for (int ks = 0; ks < 2; ++ks)
#pragma unroll
        for (int nf = 0; nf < 4; ++nf) {
          int row = nf * 16 + c;
          bfrag vf = *(const bfrag*)&Vs[cur][row * 64 + ((ks * 32 + g * 8) ^ ((row & 7) << 3))];
          acc[nf] = mfma16(vf, pa[ks], acc[nf]);
        }
      __builtin_amdgcn_s_setprio(0);

      __syncthreads();
      cur ^= 1;
    }
  }
#undef STAGE

  const float inv = 1.f / lsum;
#pragma unroll
  for (int nf = 0; nf < 4; ++nf) {
    u16x4 ov;
    if (qrow < fz) {
#pragma unroll
      for (int j = 0; j < 4; ++j)
        ov[j] = f2b(colsumg[bh * 64 + nf * 16 + g * 4 + j] * (1.f / 2048.f));
    } else {
#pragma unroll
      for (int j = 0; j < 4; ++j) ov[j] = f2b(acc[nf][j] * inv);
    }
    *(u16x4*)&ao[((size_t)b * S + qrow) * 1024 + h * 64 + nf * 16 + g * 4] = ov;
  }
}

// ---------------- launch ----------------
extern "C" void kernel_launch(void* const* d_in, const int* in_sizes, int n_in,
                              void* d_out, int out_size, void* d_ws, size_t ws_size,
                              hipStream_t stream)
{
  const float* Q  = (const float*)d_in[0];
  const float* Kk = (const float*)d_in[1];
  const float* V  = (const float*)d_in[2];
  const int* pad  = (const int*)d_in[3];
  const float* Wq = (const float*)d_in[4];
  const float* bq = (const float*)d_in[5];
  const float* Wk = (const float*)d_in[6];
  const float* bk = (const float*)d_in[7];
  const float* Wv = (const float*)d_in[8];
  const float* bv = (const float*)d_in[9];
  const float* Wo = (const float*)d_in[10];
  const float* bo = (const float*)d_in[11];

  u16* ws  = (u16*)d_ws;
  u16* WoT = ws + 3 * (size_t)(1u << 20);
  u16* qb  = ws + 4 * (size_t)(1u << 20);
  u16* kb  = ws + 8 * (size_t)(1u << 20);
  u16* vb  = ws + 12 * (size_t)(1u << 20);
  u16* Abf = ws + 20 * (size_t)(1u << 20);
  u16* kc  = ws + 20 * (size_t)(1u << 20);
  u16* vTc = ws + 24 * (size_t)(1u << 20);
  u16* ao  = vb;
  float* colsumg = (float*)(ws + (1u << 20));
  u16* idxc = ws + (1u << 20) + 4096;
  int* eqt  = (int*)(ws + (1u << 20) + 8192);

  const bool big = ws_size >= (size_t)64 * 1024 * 1024;

  wtrans_kernel<<<dim3(16, 16, 4), 256, 0, stream>>>(Wq, Wk, Wv, Wo, ws);
  if (big) {
    cvt_kernel<<<dim3(2048, 3), 256, 0, stream>>>(Q, Kk, V, Abf);
    qkv_gemm_b16<<<1536, 256, 0, stream>>>(Abf, ws, bq, bk, bv, ws);
  } else {
    qkv_gemm_f32<<<dim3(16, 32, 3), 256, 0, stream>>>(Q, Kk, V, ws, bq, bk, bv, ws);
  }
  pscan_kernel<<<2, 256, 0, stream>>>(pad, idxc, eqt, colsumg);
  colsum_kernel<<<256, 256, 0, stream>>>(vb, colsumg);
  kvgather_kernel<<<dim3(32, 32), 256, 0, stream>>>(kb, vb, idxc, kc, vTc);
  attn_kernel<<<1024, 256, 0, stream>>>(qb, kc, vTc, idxc, eqt, colsumg, ao);
  out_gemm<<<512, 256, 0, stream>>>(ao, WoT, bo, d_out);
}